// Round 1
// baseline (449.055 us; speedup 1.0000x reference)
//
#include <hip/hip_runtime.h>

typedef _Float16 f16;
typedef _Float16 half8 __attribute__((ext_vector_type(8)));
typedef float f32x4 __attribute__((ext_vector_type(4)));

#define NN 2048
#define BB 32
#define CINC 32
#define HH 64
#define DD 64
#define C1 96      // CIN + H
#define BCW 3072   // BB * C1
#define KI 192     // 2 * C1
#define OG 128
#define OU 64
#define NCHUNK 512

__device__ __forceinline__ f32x4 mfma16(half8 a, half8 b, f32x4 c) {
  return __builtin_amdgcn_mfma_f32_16x16x32_f16(a, b, c, 0, 0, 0);
}

// ---------------- LayerNorm -> e (gate & update), f32 + fp16 copies ----------------
__global__ __launch_bounds__(256) void k_ln_e(
    const float* __restrict__ ne, const float* __restrict__ te,
    const float* __restrict__ gg, const float* __restrict__ gb,
    const float* __restrict__ ug, const float* __restrict__ ub,
    float* __restrict__ eg, float* __restrict__ eu,
    f16* __restrict__ egh, f16* __restrict__ euh) {
  int node = blockIdx.x * 4 + (threadIdx.x >> 6);
  int d = threadIdx.x & 63;
  float v = ne[node * DD + d] + te[d];
  float s = v;
  #pragma unroll
  for (int m = 1; m < 64; m <<= 1) s += __shfl_xor(s, m, 64);
  float mu = s * (1.f / 64.f);
  float df = v - mu;
  float q = df * df;
  #pragma unroll
  for (int m = 1; m < 64; m <<= 1) q += __shfl_xor(q, m, 64);
  float rs = rsqrtf(q * (1.f / 64.f) + 1e-12f);
  float base = df * rs;
  float a = base * gg[d] + gb[d];
  float b = base * ug[d] + ub[d];
  eg[node * DD + d] = a; egh[node * DD + d] = (f16)a;
  eu[node * DD + d] = b; euh[node * DD + d] = (f16)b;
}

// ---------------- bias = e @ bpool (f32) ----------------
__global__ void k_bias(const float* __restrict__ e, const float* __restrict__ bpool,
                       float* __restrict__ bias, int O) {
  __shared__ float es[64];
  int n = blockIdx.x;
  int o = threadIdx.x;
  if (o < 64) es[o] = e[n * DD + o];
  __syncthreads();
  float acc = 0.f;
  #pragma unroll 8
  for (int d = 0; d < 64; ++d) acc += es[d] * bpool[d * O + o];
  bias[(size_t)n * O + o] = acc;
}

// ---------------- wpool (d,ki,o) f32 -> wpool_t (o,ki,d) fp16 ----------------
__global__ __launch_bounds__(256) void k_wpool_t(const float* __restrict__ wpool,
                                                 f16* __restrict__ wt, int O) {
  __shared__ float tile[64][17];
  int ki = blockIdx.x;
  int o0 = blockIdx.y * 16;
  int t = threadIdx.x;
  #pragma unroll
  for (int i = 0; i < 4; ++i) {
    int e2 = i * 256 + t;
    int d = e2 >> 4, o = e2 & 15;
    tile[d][o] = wpool[((size_t)d * KI + ki) * O + o0 + o];
  }
  __syncthreads();
  #pragma unroll
  for (int i = 0; i < 4; ++i) {
    int e2 = i * 256 + t;
    int o = e2 >> 6, d = e2 & 63;
    wt[((size_t)(o0 + o) * KI + ki) * DD + d] = (f16)tile[d][o];
  }
}

// ---------------- inp_nbc[m][b][c] fp16 ----------------
__global__ __launch_bounds__(256) void k_build_inp_nbc(const float* __restrict__ x,
                                                       const float* __restrict__ st,
                                                       f16* __restrict__ out) {
  size_t total = (size_t)NN * BB * C1;
  for (size_t idx = (size_t)blockIdx.x * 256 + threadIdx.x; idx < total;
       idx += (size_t)gridDim.x * 256) {
    int c = (int)(idx % C1);
    size_t t2 = idx / C1;
    int b = (int)(t2 % BB);
    int m = (int)(t2 / BB);
    float v = (c < CINC) ? x[((size_t)b * NN + m) * CINC + c]
                         : st[((size_t)b * NN + m) * HH + (c - CINC)];
    out[idx] = (f16)v;
  }
}

// ---------------- inp_cm[b][c][m] fp16 (LDS transpose) ----------------
__global__ __launch_bounds__(256) void k_build_inp_cm(const float* __restrict__ x,
                                                      const float* __restrict__ st,
                                                      f16* __restrict__ out) {
  __shared__ f16 tile[96][66];
  int mb = blockIdx.x * 64;
  int b = blockIdx.y;
  int t = threadIdx.x;
  #pragma unroll
  for (int i = 0; i < 24; ++i) {
    int e2 = i * 256 + t;  // 0..6143
    int m = e2 / 96, c = e2 % 96;
    float v = (c < CINC) ? x[((size_t)b * NN + mb + m) * CINC + c]
                         : st[((size_t)b * NN + mb + m) * HH + c - CINC];
    tile[c][m] = (f16)v;
  }
  __syncthreads();
  #pragma unroll
  for (int i = 0; i < 24; ++i) {
    int e2 = i * 256 + t;
    int c = e2 >> 6, m = e2 & 63;
    out[((size_t)b * C1 + c) * NN + mb + m] = tile[c][m];
  }
}

// ---------------- zs[b][m][o] -> cand_cm[b][32+o][m] ----------------
__global__ __launch_bounds__(256) void k_transpose_zs(const f16* __restrict__ zs,
                                                      f16* __restrict__ cm) {
  __shared__ f16 tile[64][66];
  int mb = blockIdx.x * 64;
  int b = blockIdx.y;
  int t = threadIdx.x;
  #pragma unroll
  for (int i = 0; i < 16; ++i) {
    int e2 = i * 256 + t;
    int m = e2 >> 6, o = e2 & 63;
    tile[o][m] = zs[((size_t)b * NN + mb + m) * HH + o];
  }
  __syncthreads();
  #pragma unroll
  for (int i = 0; i < 16; ++i) {
    int e2 = i * 256 + t;
    int o = e2 >> 6, m = e2 & 63;
    cm[((size_t)b * C1 + CINC + o) * NN + mb + m] = tile[o][m];
  }
}

// ---------------- S = e @ e^T  (f32, 32x32 tiles) ----------------
__global__ __launch_bounds__(256) void k_scores(const float* __restrict__ e,
                                                float* __restrict__ S) {
  __shared__ float er[32][65];
  __shared__ float ec[32][65];
  int rb = blockIdx.y * 32, cbb = blockIdx.x * 32;
  int t = threadIdx.x;
  {
    int row = t >> 3;
    int d0 = (t & 7) * 8;
    const float* pr = &e[(size_t)(rb + row) * DD + d0];
    const float* pc = &e[(size_t)(cbb + row) * DD + d0];
    #pragma unroll
    for (int j = 0; j < 8; ++j) { er[row][d0 + j] = pr[j]; ec[row][d0 + j] = pc[j]; }
  }
  __syncthreads();
  int r = t >> 5;   // 0..7
  int c = t & 31;
  float a0 = 0.f, a1 = 0.f, a2 = 0.f, a3 = 0.f;
  #pragma unroll 8
  for (int d = 0; d < 64; ++d) {
    float vc = ec[c][d];
    a0 += er[r][d] * vc;
    a1 += er[r + 8][d] * vc;
    a2 += er[r + 16][d] * vc;
    a3 += er[r + 24][d] * vc;
  }
  S[(size_t)(rb + r) * NN + cbb + c] = a0;
  S[(size_t)(rb + r + 8) * NN + cbb + c] = a1;
  S[(size_t)(rb + r + 16) * NN + cbb + c] = a2;
  S[(size_t)(rb + r + 24) * NN + cbb + c] = a3;
}

// ---------------- row softmax -> adj fp16 ----------------
__global__ __launch_bounds__(256) void k_softmax(const float* __restrict__ S,
                                                 f16* __restrict__ adj) {
  int n = blockIdx.x;
  int t = threadIdx.x;
  const float* row = S + (size_t)n * NN;
  float v[8];
  float mx = -3.0e38f;
  #pragma unroll
  for (int i = 0; i < 8; ++i) { v[i] = row[t + i * 256]; mx = fmaxf(mx, v[i]); }
  #pragma unroll
  for (int m = 1; m < 64; m <<= 1) mx = fmaxf(mx, __shfl_xor(mx, m, 64));
  __shared__ float redm[4];
  if ((t & 63) == 0) redm[t >> 6] = mx;
  __syncthreads();
  mx = fmaxf(fmaxf(redm[0], redm[1]), fmaxf(redm[2], redm[3]));
  float s = 0.f;
  #pragma unroll
  for (int i = 0; i < 8; ++i) { v[i] = expf(v[i] - mx); s += v[i]; }
  #pragma unroll
  for (int m = 1; m < 64; m <<= 1) s += __shfl_xor(s, m, 64);
  __shared__ float reds[4];
  if ((t & 63) == 0) reds[t >> 6] = s;
  __syncthreads();
  s = reds[0] + reds[1] + reds[2] + reds[3];
  float inv = 1.f / s;
  #pragma unroll
  for (int i = 0; i < 8; ++i) adj[(size_t)n * NN + t + i * 256] = (f16)(v[i] * inv);
}

// ---------------- xaT(n, b*96+c) = adj(n,m) @ inp_cm(bc, m)^T ----------------
__global__ __launch_bounds__(256) void k_gemm_xa(const f16* __restrict__ adj,
                                                 const f16* __restrict__ bt,
                                                 f16* __restrict__ out) {
  __shared__ f16 As[64][56];
  __shared__ f16 Bs[64][56];
  int nb = blockIdx.y * 64;
  int cb = blockIdx.x * 64;
  int tid = threadIdx.x;
  int w = tid >> 6, lane = tid & 63;
  int wr = (w >> 1) * 32, wc = (w & 1) * 32;
  int fr = lane & 15, fk = (lane >> 4) * 8;
  int srow = tid >> 2;
  int skoff = (tid & 3) * 8;
  f32x4 acc[2][2] = {};
  for (int kt = 0; kt < NN; kt += 32) {
    *(half8*)&As[srow][skoff] = *(const half8*)&adj[(size_t)(nb + srow) * NN + kt + skoff];
    *(half8*)&Bs[srow][skoff] = *(const half8*)&bt[(size_t)(cb + srow) * NN + kt + skoff];
    __syncthreads();
    half8 a0 = *(const half8*)&As[wr + fr][fk];
    half8 a1 = *(const half8*)&As[wr + 16 + fr][fk];
    half8 b0 = *(const half8*)&Bs[wc + fr][fk];
    half8 b1 = *(const half8*)&Bs[wc + 16 + fr][fk];
    acc[0][0] = mfma16(a0, b0, acc[0][0]);
    acc[0][1] = mfma16(a0, b1, acc[0][1]);
    acc[1][0] = mfma16(a1, b0, acc[1][0]);
    acc[1][1] = mfma16(a1, b1, acc[1][1]);
    __syncthreads();
  }
  #pragma unroll
  for (int mt = 0; mt < 2; ++mt)
    #pragma unroll
    for (int nt = 0; nt < 2; ++nt)
      #pragma unroll
      for (int r = 0; r < 4; ++r) {
        int n = nb + wr + mt * 16 + (lane >> 4) * 4 + r;
        int c = cb + wc + nt * 16 + fr;
        out[(size_t)n * BCW + c] = (f16)acc[mt][nt][r];
      }
}

// ---------------- W chunk: W[nloc, o*KI+ki] = e(n,d) @ wpool_t((o,ki), d)^T ----------------
__global__ __launch_bounds__(256) void k_gemm_w(const f16* __restrict__ eh,
                                                const f16* __restrict__ wt2,
                                                f16* __restrict__ W, int NCK) {
  int cb = blockIdx.x * 64, nb = blockIdx.y * 64;
  int lane = threadIdx.x & 63, w = threadIdx.x >> 6;
  int wr = (w >> 1) * 32, wc = (w & 1) * 32;
  int fr = lane & 15, fk = (lane >> 4) * 8;
  f32x4 acc[2][2] = {};
  #pragma unroll
  for (int ks = 0; ks < 64; ks += 32) {
    half8 a0 = *(const half8*)&eh[(size_t)(nb + wr + fr) * DD + ks + fk];
    half8 a1 = *(const half8*)&eh[(size_t)(nb + wr + 16 + fr) * DD + ks + fk];
    half8 b0 = *(const half8*)&wt2[(size_t)(cb + wc + fr) * DD + ks + fk];
    half8 b1 = *(const half8*)&wt2[(size_t)(cb + wc + 16 + fr) * DD + ks + fk];
    acc[0][0] = mfma16(a0, b0, acc[0][0]);
    acc[0][1] = mfma16(a0, b1, acc[0][1]);
    acc[1][0] = mfma16(a1, b0, acc[1][0]);
    acc[1][1] = mfma16(a1, b1, acc[1][1]);
  }
  #pragma unroll
  for (int mt = 0; mt < 2; ++mt)
    #pragma unroll
    for (int nt = 0; nt < 2; ++nt)
      #pragma unroll
      for (int r = 0; r < 4; ++r) {
        int n = nb + wr + mt * 16 + (lane >> 4) * 4 + r;
        int c = cb + wc + nt * 16 + fr;
        W[(size_t)n * NCK + c] = (f16)acc[mt][nt][r];
      }
}

// ---------------- apply: out(b,n,o) = Xg(b, ki) @ W[n](ki, o) + bias, + epilogues ----------------
template <int O, bool GATE>
__global__ __launch_bounds__(256) void k_apply(
    const f16* nbc, const f16* __restrict__ xaT, const f16* __restrict__ W,
    const float* __restrict__ bias, const float* __restrict__ state,
    f16* nbc_w, f16* zs, float* __restrict__ rbuf, float* __restrict__ outp, int n0) {
  int n = n0 + blockIdx.x;
  int lane = threadIdx.x & 63, w = threadIdx.x >> 6;
  int fr = lane & 15, fq = lane >> 4;
  half8 af[2][6];
  #pragma unroll
  for (int mt = 0; mt < 2; ++mt) {
    int b = mt * 16 + fr;
    const f16* prow = nbc + ((size_t)n * BB + b) * C1;
    const f16* xrow = xaT + ((size_t)n * BB + b) * C1;
    #pragma unroll
    for (int ks = 0; ks < 6; ++ks) {
      int ki = ks * 32 + fq * 8;
      af[mt][ks] = (ki < 96) ? *(const half8*)&prow[ki] : *(const half8*)&xrow[ki - 96];
    }
  }
  __syncthreads();  // all A-frag reads complete before any epilogue writes to nbc
  constexpr int NOT_ = GATE ? 2 : 1;
  f32x4 acc[2][NOT_] = {};
  #pragma unroll
  for (int ks = 0; ks < 6; ++ks) {
    #pragma unroll
    for (int ot = 0; ot < NOT_; ++ot) {
      int o = (GATE ? (w * 2 + ot) : w) * 16 + fr;
      half8 bf = *(const half8*)&W[((size_t)blockIdx.x * O + o) * KI + ks * 32 + fq * 8];
      #pragma unroll
      for (int mt = 0; mt < 2; ++mt) acc[mt][ot] = mfma16(af[mt][ks], bf, acc[mt][ot]);
    }
  }
  #pragma unroll
  for (int mt = 0; mt < 2; ++mt)
    #pragma unroll
    for (int ot = 0; ot < NOT_; ++ot) {
      int o = (GATE ? (w * 2 + ot) : w) * 16 + fr;
      float bs = bias[(size_t)n * O + o];
      #pragma unroll
      for (int r = 0; r < 4; ++r) {
        int b = mt * 16 + fq * 4 + r;
        float val = acc[mt][ot][r] + bs;
        if (GATE) {
          float s = 1.f / (1.f + expf(-val));
          if (o < HH) {
            float zst = s * state[((size_t)b * NN + n) * HH + o];
            nbc_w[((size_t)n * BB + b) * C1 + CINC + o] = (f16)zst;
            zs[((size_t)b * NN + n) * HH + o] = (f16)zst;
          } else {
            rbuf[((size_t)b * NN + n) * HH + (o - HH)] = s;
          }
        } else {
          float hc = tanhf(val);
          float rr = rbuf[((size_t)b * NN + n) * HH + o];
          float st = state[((size_t)b * NN + n) * HH + o];
          outp[((size_t)b * NN + n) * HH + o] = rr * st + (1.f - rr) * hc;
        }
      }
    }
}

extern "C" void kernel_launch(void* const* d_in, const int* in_sizes, int n_in,
                              void* d_out, int out_size, void* d_ws, size_t ws_size,
                              hipStream_t stream) {
  const float* x   = (const float*)d_in[0];
  const float* st  = (const float*)d_in[1];
  const float* ne  = (const float*)d_in[2];
  const float* te  = (const float*)d_in[3];
  const float* gwp = (const float*)d_in[4];
  const float* gbp = (const float*)d_in[5];
  const float* gg  = (const float*)d_in[6];
  const float* gb  = (const float*)d_in[7];
  const float* uwp = (const float*)d_in[8];
  const float* ubp = (const float*)d_in[9];
  const float* ug  = (const float*)d_in[10];
  const float* ub  = (const float*)d_in[11];
  float* out = (float*)d_out;

  char* wsb = (char*)d_ws;
  size_t off = 0;
  auto alloc = [&](size_t bytes) {
    char* p = wsb + off;
    off = (off + bytes + 255) & ~(size_t)255;
    return p;
  };
  float* e_g   = (float*)alloc((size_t)NN * DD * 4);
  float* e_u   = (float*)alloc((size_t)NN * DD * 4);
  f16*   egh   = (f16*)  alloc((size_t)NN * DD * 2);
  f16*   euh   = (f16*)  alloc((size_t)NN * DD * 2);
  float* biasg = (float*)alloc((size_t)NN * OG * 4);
  float* biasu = (float*)alloc((size_t)NN * OU * 4);
  f16*   wtg   = (f16*)  alloc((size_t)OG * KI * DD * 2);
  f16*   wtu   = (f16*)  alloc((size_t)OU * KI * DD * 2);
  float* S     = (float*)alloc((size_t)NN * NN * 4);
  f16*   adj   = (f16*)  alloc((size_t)NN * NN * 2);
  f16*   nbc   = (f16*)  alloc((size_t)NN * BB * C1 * 2);
  f16*   cm    = (f16*)  alloc((size_t)BB * C1 * NN * 2);
  f16*   xaT   = (f16*)  alloc((size_t)NN * BB * C1 * 2);
  f16*   W     = (f16*)  alloc((size_t)NCHUNK * OG * KI * 2);
  f16*   zs    = (f16*)  alloc((size_t)BB * NN * HH * 2);
  float* rbuf  = (float*)alloc((size_t)BB * NN * HH * 4);
  (void)ws_size; (void)in_sizes; (void)n_in; (void)out_size;

  hipLaunchKernelGGL(k_ln_e, dim3(NN / 4), dim3(256), 0, stream,
                     ne, te, gg, gb, ug, ub, e_g, e_u, egh, euh);
  hipLaunchKernelGGL(k_bias, dim3(NN), dim3(OG), 0, stream, e_g, gbp, biasg, OG);
  hipLaunchKernelGGL(k_bias, dim3(NN), dim3(OU), 0, stream, e_u, ubp, biasu, OU);
  hipLaunchKernelGGL(k_wpool_t, dim3(KI, OG / 16), dim3(256), 0, stream, gwp, wtg, OG);
  hipLaunchKernelGGL(k_wpool_t, dim3(KI, OU / 16), dim3(256), 0, stream, uwp, wtu, OU);
  hipLaunchKernelGGL(k_build_inp_nbc, dim3(4096), dim3(256), 0, stream, x, st, nbc);
  hipLaunchKernelGGL(k_build_inp_cm, dim3(NN / 64, BB), dim3(256), 0, stream, x, st, cm);

  // ---- gate GCN ----
  hipLaunchKernelGGL(k_scores, dim3(NN / 32, NN / 32), dim3(256), 0, stream, e_g, S);
  hipLaunchKernelGGL(k_softmax, dim3(NN), dim3(256), 0, stream, S, adj);
  hipLaunchKernelGGL(k_gemm_xa, dim3(BCW / 64, NN / 64), dim3(256), 0, stream, adj, cm, xaT);
  for (int ch = 0; ch < NN / NCHUNK; ++ch) {
    hipLaunchKernelGGL(k_gemm_w, dim3(OG * KI / 64, NCHUNK / 64), dim3(256), 0, stream,
                       egh + (size_t)ch * NCHUNK * DD, wtg, W, OG * KI);
    hipLaunchKernelGGL((k_apply<OG, true>), dim3(NCHUNK), dim3(256), 0, stream,
                       nbc, xaT, W, biasg, st, nbc, zs, rbuf, (float*)nullptr, ch * NCHUNK);
  }
  hipLaunchKernelGGL(k_transpose_zs, dim3(NN / 64, BB), dim3(256), 0, stream, zs, cm);

  // ---- update GCN ----
  hipLaunchKernelGGL(k_scores, dim3(NN / 32, NN / 32), dim3(256), 0, stream, e_u, S);
  hipLaunchKernelGGL(k_softmax, dim3(NN), dim3(256), 0, stream, S, adj);
  hipLaunchKernelGGL(k_gemm_xa, dim3(BCW / 64, NN / 64), dim3(256), 0, stream, adj, cm, xaT);
  for (int ch = 0; ch < NN / NCHUNK; ++ch) {
    hipLaunchKernelGGL(k_gemm_w, dim3(OU * KI / 64, NCHUNK / 64), dim3(256), 0, stream,
                       euh + (size_t)ch * NCHUNK * DD, wtu, W, OU * KI);
    hipLaunchKernelGGL((k_apply<OU, false>), dim3(NCHUNK), dim3(256), 0, stream,
                       nbc, xaT, W, biasu, st, nbc, (f16*)nullptr, rbuf, out, ch * NCHUNK);
  }
}

// Round 2
// 378.171 us; speedup vs baseline: 1.1874x; 1.1874x over previous
//
#include <hip/hip_runtime.h>

typedef _Float16 f16;
typedef _Float16 half8 __attribute__((ext_vector_type(8)));
typedef float f32x4 __attribute__((ext_vector_type(4)));

#define NN 2048
#define BB 32
#define CINC 32
#define HH 64
#define DD 64
#define C1 96      // CIN + H
#define BCW 3072   // BB * C1
#define KI 192     // 2 * C1
#define OG 128
#define OU 64
#define NCHUNK 512

__device__ __forceinline__ f32x4 mfma16(half8 a, half8 b, f32x4 c) {
  return __builtin_amdgcn_mfma_f32_16x16x32_f16(a, b, c, 0, 0, 0);
}

typedef __attribute__((address_space(1))) const void* gas_t;
typedef __attribute__((address_space(3))) void* las_t;
__device__ __forceinline__ void gl_lds16(const void* g, void* l) {
  __builtin_amdgcn_global_load_lds((gas_t)g, (las_t)l, 16, 0, 0);
}

// ---------------- LayerNorm -> e (gate & update), f32 + fp16 copies ----------------
__global__ __launch_bounds__(256) void k_ln_e(
    const float* __restrict__ ne, const float* __restrict__ te,
    const float* __restrict__ gg, const float* __restrict__ gb,
    const float* __restrict__ ug, const float* __restrict__ ub,
    float* __restrict__ eg, float* __restrict__ eu,
    f16* __restrict__ egh, f16* __restrict__ euh) {
  int node = blockIdx.x * 4 + (threadIdx.x >> 6);
  int d = threadIdx.x & 63;
  float v = ne[node * DD + d] + te[d];
  float s = v;
  #pragma unroll
  for (int m = 1; m < 64; m <<= 1) s += __shfl_xor(s, m, 64);
  float mu = s * (1.f / 64.f);
  float df = v - mu;
  float q = df * df;
  #pragma unroll
  for (int m = 1; m < 64; m <<= 1) q += __shfl_xor(q, m, 64);
  float rs = rsqrtf(q * (1.f / 64.f) + 1e-12f);
  float base = df * rs;
  float a = base * gg[d] + gb[d];
  float b = base * ug[d] + ub[d];
  eg[node * DD + d] = a; egh[node * DD + d] = (f16)a;
  eu[node * DD + d] = b; euh[node * DD + d] = (f16)b;
}

// ---------------- bias = e @ bpool (f32) ----------------
__global__ void k_bias(const float* __restrict__ e, const float* __restrict__ bpool,
                       float* __restrict__ bias, int O) {
  __shared__ float es[64];
  int n = blockIdx.x;
  int o = threadIdx.x;
  if (o < 64) es[o] = e[n * DD + o];
  __syncthreads();
  float acc = 0.f;
  #pragma unroll 8
  for (int d = 0; d < 64; ++d) acc += es[d] * bpool[d * O + o];
  bias[(size_t)n * O + o] = acc;
}

// ---------------- wpool (d,ki,o) f32 -> wpool_t (o,ki,d) fp16 ----------------
__global__ __launch_bounds__(256) void k_wpool_t(const float* __restrict__ wpool,
                                                 f16* __restrict__ wt, int O) {
  __shared__ float tile[64][17];
  int ki = blockIdx.x;
  int o0 = blockIdx.y * 16;
  int t = threadIdx.x;
  #pragma unroll
  for (int i = 0; i < 4; ++i) {
    int e2 = i * 256 + t;
    int d = e2 >> 4, o = e2 & 15;
    tile[d][o] = wpool[((size_t)d * KI + ki) * O + o0 + o];
  }
  __syncthreads();
  #pragma unroll
  for (int i = 0; i < 4; ++i) {
    int e2 = i * 256 + t;
    int o = e2 >> 6, d = e2 & 63;
    wt[((size_t)(o0 + o) * KI + ki) * DD + d] = (f16)tile[d][o];
  }
}

// ---------------- inp_nbc[m][b][c] fp16 ----------------
__global__ __launch_bounds__(256) void k_build_inp_nbc(const float* __restrict__ x,
                                                       const float* __restrict__ st,
                                                       f16* __restrict__ out) {
  size_t total = (size_t)NN * BB * C1;
  for (size_t idx = (size_t)blockIdx.x * 256 + threadIdx.x; idx < total;
       idx += (size_t)gridDim.x * 256) {
    int c = (int)(idx % C1);
    size_t t2 = idx / C1;
    int b = (int)(t2 % BB);
    int m = (int)(t2 / BB);
    float v = (c < CINC) ? x[((size_t)b * NN + m) * CINC + c]
                         : st[((size_t)b * NN + m) * HH + (c - CINC)];
    out[idx] = (f16)v;
  }
}

// ---------------- inp_cm[b][c][m] fp16 (LDS transpose) ----------------
__global__ __launch_bounds__(256) void k_build_inp_cm(const float* __restrict__ x,
                                                      const float* __restrict__ st,
                                                      f16* __restrict__ out) {
  __shared__ f16 tile[96][66];
  int mb = blockIdx.x * 64;
  int b = blockIdx.y;
  int t = threadIdx.x;
  #pragma unroll
  for (int i = 0; i < 24; ++i) {
    int e2 = i * 256 + t;  // 0..6143
    int m = e2 / 96, c = e2 % 96;
    float v = (c < CINC) ? x[((size_t)b * NN + mb + m) * CINC + c]
                         : st[((size_t)b * NN + mb + m) * HH + c - CINC];
    tile[c][m] = (f16)v;
  }
  __syncthreads();
  #pragma unroll
  for (int i = 0; i < 24; ++i) {
    int e2 = i * 256 + t;
    int c = e2 >> 6, m = e2 & 63;
    out[((size_t)b * C1 + c) * NN + mb + m] = tile[c][m];
  }
}

// ---------------- zs[b][m][o] -> cand_cm[b][32+o][m] ----------------
__global__ __launch_bounds__(256) void k_transpose_zs(const f16* __restrict__ zs,
                                                      f16* __restrict__ cm) {
  __shared__ f16 tile[64][66];
  int mb = blockIdx.x * 64;
  int b = blockIdx.y;
  int t = threadIdx.x;
  #pragma unroll
  for (int i = 0; i < 16; ++i) {
    int e2 = i * 256 + t;
    int m = e2 >> 6, o = e2 & 63;
    tile[o][m] = zs[((size_t)b * NN + mb + m) * HH + o];
  }
  __syncthreads();
  #pragma unroll
  for (int i = 0; i < 16; ++i) {
    int e2 = i * 256 + t;
    int o = e2 >> 6, m = e2 & 63;
    cm[((size_t)b * C1 + CINC + o) * NN + mb + m] = tile[o][m];
  }
}

// ---------------- S = e @ e^T  (f32, 32x32 tiles) ----------------
__global__ __launch_bounds__(256) void k_scores(const float* __restrict__ e,
                                                float* __restrict__ S) {
  __shared__ float er[32][65];
  __shared__ float ec[32][65];
  int rb = blockIdx.y * 32, cbb = blockIdx.x * 32;
  int t = threadIdx.x;
  {
    int row = t >> 3;
    int d0 = (t & 7) * 8;
    const float* pr = &e[(size_t)(rb + row) * DD + d0];
    const float* pc = &e[(size_t)(cbb + row) * DD + d0];
    #pragma unroll
    for (int j = 0; j < 8; ++j) { er[row][d0 + j] = pr[j]; ec[row][d0 + j] = pc[j]; }
  }
  __syncthreads();
  int r = t >> 5;   // 0..7
  int c = t & 31;
  float a0 = 0.f, a1 = 0.f, a2 = 0.f, a3 = 0.f;
  #pragma unroll 8
  for (int d = 0; d < 64; ++d) {
    float vc = ec[c][d];
    a0 += er[r][d] * vc;
    a1 += er[r + 8][d] * vc;
    a2 += er[r + 16][d] * vc;
    a3 += er[r + 24][d] * vc;
  }
  S[(size_t)(rb + r) * NN + cbb + c] = a0;
  S[(size_t)(rb + r + 8) * NN + cbb + c] = a1;
  S[(size_t)(rb + r + 16) * NN + cbb + c] = a2;
  S[(size_t)(rb + r + 24) * NN + cbb + c] = a3;
}

// ---------------- row softmax -> adj fp16 ----------------
__global__ __launch_bounds__(256) void k_softmax(const float* __restrict__ S,
                                                 f16* __restrict__ adj) {
  int n = blockIdx.x;
  int t = threadIdx.x;
  const float* row = S + (size_t)n * NN;
  float v[8];
  float mx = -3.0e38f;
  #pragma unroll
  for (int i = 0; i < 8; ++i) { v[i] = row[t + i * 256]; mx = fmaxf(mx, v[i]); }
  #pragma unroll
  for (int m = 1; m < 64; m <<= 1) mx = fmaxf(mx, __shfl_xor(mx, m, 64));
  __shared__ float redm[4];
  if ((t & 63) == 0) redm[t >> 6] = mx;
  __syncthreads();
  mx = fmaxf(fmaxf(redm[0], redm[1]), fmaxf(redm[2], redm[3]));
  float s = 0.f;
  #pragma unroll
  for (int i = 0; i < 8; ++i) { v[i] = expf(v[i] - mx); s += v[i]; }
  #pragma unroll
  for (int m = 1; m < 64; m <<= 1) s += __shfl_xor(s, m, 64);
  __shared__ float reds[4];
  if ((t & 63) == 0) reds[t >> 6] = s;
  __syncthreads();
  s = reds[0] + reds[1] + reds[2] + reds[3];
  float inv = 1.f / s;
  #pragma unroll
  for (int i = 0; i < 8; ++i) adj[(size_t)n * NN + t + i * 256] = (f16)(v[i] * inv);
}

// ---------------- xaT(n, bc) = adj(n,m) @ cm(bc, m)^T ----------------
// 128x96 tile, BK=64, global_load_lds(16B) staging, swizzled LDS (linear dest +
// pre-swizzled global source + swizzled ds_read -- rule #21 both-sides).
#define BM 128
#define BN 96
#define SWZ(row, kb) (((row) << 7) + ((kb) ^ (((row) & 7) << 4)))

__global__ __launch_bounds__(256, 2) void k_gemm_xa(const f16* __restrict__ A,
                                                    const f16* __restrict__ B,
                                                    f16* __restrict__ C) {
  __shared__ f16 Al[BM * 64];
  __shared__ f16 Bl[BN * 64];
  const int nb = blockIdx.x * BM;   // x = n-tile (16) so each XCD owns 2 A-panels
  const int cb = blockIdx.y * BN;   // y = c-tile (32)
  const int tid = threadIdx.x;
  const int w = tid >> 6, lane = tid & 63;
  const int wr = (w >> 1) * 64, wc = (w & 1) * 48;
  const int fr = lane & 15, fq = lane >> 4;

  // staging source: chunk j covers rows j*32 + (tid>>3); 8 lanes per row.
  const int arow = tid >> 3;                       // 0..31
  const int acolb = ((tid & 7) * 16) ^ ((arow & 7) << 4);  // pre-swizzled, j-invariant
  const char* asrc = (const char*)A + (size_t)(nb + arow) * (NN * 2) + acolb;
  const char* bsrc = (const char*)B + (size_t)(cb + arow) * (NN * 2) + acolb;
  char* aldst = (char*)Al + (w << 10);
  char* bldst = (char*)Bl + (w << 10);

  f32x4 acc[4][3] = {};
  for (int kt = 0; kt < NN; kt += 64) {
    const size_t ko = (size_t)kt * 2;
    #pragma unroll
    for (int j = 0; j < 4; ++j)
      gl_lds16(asrc + ko + (size_t)j * 32 * (NN * 2), aldst + j * 4096);
    #pragma unroll
    for (int j = 0; j < 3; ++j)
      gl_lds16(bsrc + ko + (size_t)j * 32 * (NN * 2), bldst + j * 4096);
    __syncthreads();
    #pragma unroll
    for (int k0 = 0; k0 < 2; ++k0) {
      const int kb = k0 * 64 + fq * 16;
      half8 af[4], bf[3];
      #pragma unroll
      for (int mt = 0; mt < 4; ++mt) {
        int row = wr + mt * 16 + fr;
        af[mt] = *(const half8*)((const char*)Al + SWZ(row, kb));
      }
      #pragma unroll
      for (int nt = 0; nt < 3; ++nt) {
        int row = wc + nt * 16 + fr;
        bf[nt] = *(const half8*)((const char*)Bl + SWZ(row, kb));
      }
      #pragma unroll
      for (int mt = 0; mt < 4; ++mt)
        #pragma unroll
        for (int nt = 0; nt < 3; ++nt)
          acc[mt][nt] = mfma16(af[mt], bf[nt], acc[mt][nt]);
    }
    __syncthreads();
  }
  #pragma unroll
  for (int mt = 0; mt < 4; ++mt)
    #pragma unroll
    for (int nt = 0; nt < 3; ++nt)
      #pragma unroll
      for (int r = 0; r < 4; ++r) {
        int n = nb + wr + mt * 16 + fq * 4 + r;
        int c = cb + wc + nt * 16 + fr;
        C[(size_t)n * BCW + c] = (f16)acc[mt][nt][r];
      }
}

// ---------------- W chunk: W[nloc, o*KI+ki] = e(n,d) @ wpool_t((o,ki), d)^T ----------------
__global__ __launch_bounds__(256) void k_gemm_w(const f16* __restrict__ eh,
                                                const f16* __restrict__ wt2,
                                                f16* __restrict__ W, int NCK) {
  int cb = blockIdx.x * 64, nb = blockIdx.y * 64;
  int lane = threadIdx.x & 63, w = threadIdx.x >> 6;
  int wr = (w >> 1) * 32, wc = (w & 1) * 32;
  int fr = lane & 15, fk = (lane >> 4) * 8;
  f32x4 acc[2][2] = {};
  #pragma unroll
  for (int ks = 0; ks < 64; ks += 32) {
    half8 a0 = *(const half8*)&eh[(size_t)(nb + wr + fr) * DD + ks + fk];
    half8 a1 = *(const half8*)&eh[(size_t)(nb + wr + 16 + fr) * DD + ks + fk];
    half8 b0 = *(const half8*)&wt2[(size_t)(cb + wc + fr) * DD + ks + fk];
    half8 b1 = *(const half8*)&wt2[(size_t)(cb + wc + 16 + fr) * DD + ks + fk];
    acc[0][0] = mfma16(a0, b0, acc[0][0]);
    acc[0][1] = mfma16(a0, b1, acc[0][1]);
    acc[1][0] = mfma16(a1, b0, acc[1][0]);
    acc[1][1] = mfma16(a1, b1, acc[1][1]);
  }
  #pragma unroll
  for (int mt = 0; mt < 2; ++mt)
    #pragma unroll
    for (int nt = 0; nt < 2; ++nt)
      #pragma unroll
      for (int r = 0; r < 4; ++r) {
        int n = nb + wr + mt * 16 + (lane >> 4) * 4 + r;
        int c = cb + wc + nt * 16 + fr;
        W[(size_t)n * NCK + c] = (f16)acc[mt][nt][r];
      }
}

// ---------------- apply: out(b,n,o) = Xg(b, ki) @ W[n](ki, o) + bias, + epilogues ----------------
template <int O, bool GATE>
__global__ __launch_bounds__(256) void k_apply(
    const f16* nbc, const f16* __restrict__ xaT, const f16* __restrict__ W,
    const float* __restrict__ bias, const float* __restrict__ state,
    f16* nbc_w, f16* zs, float* __restrict__ rbuf, float* __restrict__ outp, int n0) {
  int n = n0 + blockIdx.x;
  int lane = threadIdx.x & 63, w = threadIdx.x >> 6;
  int fr = lane & 15, fq = lane >> 4;
  half8 af[2][6];
  #pragma unroll
  for (int mt = 0; mt < 2; ++mt) {
    int b = mt * 16 + fr;
    const f16* prow = nbc + ((size_t)n * BB + b) * C1;
    const f16* xrow = xaT + ((size_t)n * BB + b) * C1;
    #pragma unroll
    for (int ks = 0; ks < 6; ++ks) {
      int ki = ks * 32 + fq * 8;
      af[mt][ks] = (ki < 96) ? *(const half8*)&prow[ki] : *(const half8*)&xrow[ki - 96];
    }
  }
  __syncthreads();  // all A-frag reads complete before any epilogue writes to nbc
  constexpr int NOT_ = GATE ? 2 : 1;
  f32x4 acc[2][NOT_] = {};
  #pragma unroll
  for (int ks = 0; ks < 6; ++ks) {
    #pragma unroll
    for (int ot = 0; ot < NOT_; ++ot) {
      int o = (GATE ? (w * 2 + ot) : w) * 16 + fr;
      half8 bf = *(const half8*)&W[((size_t)blockIdx.x * O + o) * KI + ks * 32 + fq * 8];
      #pragma unroll
      for (int mt = 0; mt < 2; ++mt) acc[mt][ot] = mfma16(af[mt][ks], bf, acc[mt][ot]);
    }
  }
  #pragma unroll
  for (int mt = 0; mt < 2; ++mt)
    #pragma unroll
    for (int ot = 0; ot < NOT_; ++ot) {
      int o = (GATE ? (w * 2 + ot) : w) * 16 + fr;
      float bs = bias[(size_t)n * O + o];
      #pragma unroll
      for (int r = 0; r < 4; ++r) {
        int b = mt * 16 + fq * 4 + r;
        float val = acc[mt][ot][r] + bs;
        if (GATE) {
          float s = 1.f / (1.f + expf(-val));
          if (o < HH) {
            float zst = s * state[((size_t)b * NN + n) * HH + o];
            nbc_w[((size_t)n * BB + b) * C1 + CINC + o] = (f16)zst;
            zs[((size_t)b * NN + n) * HH + o] = (f16)zst;
          } else {
            rbuf[((size_t)b * NN + n) * HH + (o - HH)] = s;
          }
        } else {
          float hc = tanhf(val);
          float rr = rbuf[((size_t)b * NN + n) * HH + o];
          float st = state[((size_t)b * NN + n) * HH + o];
          outp[((size_t)b * NN + n) * HH + o] = rr * st + (1.f - rr) * hc;
        }
      }
    }
}

extern "C" void kernel_launch(void* const* d_in, const int* in_sizes, int n_in,
                              void* d_out, int out_size, void* d_ws, size_t ws_size,
                              hipStream_t stream) {
  const float* x   = (const float*)d_in[0];
  const float* st  = (const float*)d_in[1];
  const float* ne  = (const float*)d_in[2];
  const float* te  = (const float*)d_in[3];
  const float* gwp = (const float*)d_in[4];
  const float* gbp = (const float*)d_in[5];
  const float* gg  = (const float*)d_in[6];
  const float* gb  = (const float*)d_in[7];
  const float* uwp = (const float*)d_in[8];
  const float* ubp = (const float*)d_in[9];
  const float* ug  = (const float*)d_in[10];
  const float* ub  = (const float*)d_in[11];
  float* out = (float*)d_out;

  char* wsb = (char*)d_ws;
  size_t off = 0;
  auto alloc = [&](size_t bytes) {
    char* p = wsb + off;
    off = (off + bytes + 255) & ~(size_t)255;
    return p;
  };
  float* e_g   = (float*)alloc((size_t)NN * DD * 4);
  float* e_u   = (float*)alloc((size_t)NN * DD * 4);
  f16*   egh   = (f16*)  alloc((size_t)NN * DD * 2);
  f16*   euh   = (f16*)  alloc((size_t)NN * DD * 2);
  float* biasg = (float*)alloc((size_t)NN * OG * 4);
  float* biasu = (float*)alloc((size_t)NN * OU * 4);
  f16*   wtg   = (f16*)  alloc((size_t)OG * KI * DD * 2);
  f16*   wtu   = (f16*)  alloc((size_t)OU * KI * DD * 2);
  float* S     = (float*)alloc((size_t)NN * NN * 4);
  f16*   adj   = (f16*)  alloc((size_t)NN * NN * 2);
  f16*   nbc   = (f16*)  alloc((size_t)NN * BB * C1 * 2);
  f16*   cm    = (f16*)  alloc((size_t)BB * C1 * NN * 2);
  f16*   xaT   = (f16*)  alloc((size_t)NN * BB * C1 * 2);
  f16*   W     = (f16*)  alloc((size_t)NCHUNK * OG * KI * 2);
  f16*   zs    = (f16*)  alloc((size_t)BB * NN * HH * 2);
  float* rbuf  = (float*)alloc((size_t)BB * NN * HH * 4);
  (void)ws_size; (void)in_sizes; (void)n_in; (void)out_size;

  hipLaunchKernelGGL(k_ln_e, dim3(NN / 4), dim3(256), 0, stream,
                     ne, te, gg, gb, ug, ub, e_g, e_u, egh, euh);
  hipLaunchKernelGGL(k_bias, dim3(NN), dim3(OG), 0, stream, e_g, gbp, biasg, OG);
  hipLaunchKernelGGL(k_bias, dim3(NN), dim3(OU), 0, stream, e_u, ubp, biasu, OU);
  hipLaunchKernelGGL(k_wpool_t, dim3(KI, OG / 16), dim3(256), 0, stream, gwp, wtg, OG);
  hipLaunchKernelGGL(k_wpool_t, dim3(KI, OU / 16), dim3(256), 0, stream, uwp, wtu, OU);
  hipLaunchKernelGGL(k_build_inp_nbc, dim3(4096), dim3(256), 0, stream, x, st, nbc);
  hipLaunchKernelGGL(k_build_inp_cm, dim3(NN / 64, BB), dim3(256), 0, stream, x, st, cm);

  // ---- gate GCN ----
  hipLaunchKernelGGL(k_scores, dim3(NN / 32, NN / 32), dim3(256), 0, stream, e_g, S);
  hipLaunchKernelGGL(k_softmax, dim3(NN), dim3(256), 0, stream, S, adj);
  hipLaunchKernelGGL(k_gemm_xa, dim3(NN / BM, BCW / BN), dim3(256), 0, stream, adj, cm, xaT);
  for (int ch = 0; ch < NN / NCHUNK; ++ch) {
    hipLaunchKernelGGL(k_gemm_w, dim3(OG * KI / 64, NCHUNK / 64), dim3(256), 0, stream,
                       egh + (size_t)ch * NCHUNK * DD, wtg, W, OG * KI);
    hipLaunchKernelGGL((k_apply<OG, true>), dim3(NCHUNK), dim3(256), 0, stream,
                       nbc, xaT, W, biasg, st, nbc, zs, rbuf, (float*)nullptr, ch * NCHUNK);
  }
  hipLaunchKernelGGL(k_transpose_zs, dim3(NN / 64, BB), dim3(256), 0, stream, zs, cm);

  // ---- update GCN ----
  hipLaunchKernelGGL(k_scores, dim3(NN / 32, NN / 32), dim3(256), 0, stream, e_u, S);
  hipLaunchKernelGGL(k_softmax, dim3(NN), dim3(256), 0, stream, S, adj);
  hipLaunchKernelGGL(k_gemm_xa, dim3(NN / BM, BCW / BN), dim3(256), 0, stream, adj, cm, xaT);
  for (int ch = 0; ch < NN / NCHUNK; ++ch) {
    hipLaunchKernelGGL(k_gemm_w, dim3(OU * KI / 64, NCHUNK / 64), dim3(256), 0, stream,
                       euh + (size_t)ch * NCHUNK * DD, wtu, W, OU * KI);
    hipLaunchKernelGGL((k_apply<OU, false>), dim3(NCHUNK), dim3(256), 0, stream,
                       nbc, xaT, W, biasu, st, nbc, (f16*)nullptr, rbuf, out, ch * NCHUNK);
  }
}

// Round 3
// 280.071 us; speedup vs baseline: 1.6034x; 1.3503x over previous
//
#include <hip/hip_runtime.h>

typedef _Float16 f16;
typedef _Float16 half8 __attribute__((ext_vector_type(8)));
typedef float f32x4 __attribute__((ext_vector_type(4)));

#define NN 2048
#define BB 32
#define CINC 32
#define HH 64
#define DD 64
#define C1 96      // CIN + H
#define BCW 3072   // BB * C1
#define KI 192     // 2 * C1
#define OG 128
#define OU 64
#define WCOLS 12288  // 64 * KI, per o-chunk of 64

__device__ __forceinline__ f32x4 mfma16(half8 a, half8 b, f32x4 c) {
  return __builtin_amdgcn_mfma_f32_16x16x32_f16(a, b, c, 0, 0, 0);
}

typedef __attribute__((address_space(1))) const void* gas_t;
typedef __attribute__((address_space(3))) void* las_t;
__device__ __forceinline__ void gl_lds16(const void* g, void* l) {
  __builtin_amdgcn_global_load_lds((gas_t)g, (las_t)l, 16, 0, 0);
}

// XOR swizzle for 128B-row LDS tiles (rule #21: pre-swizzled source + swizzled read)
#define SWZ(row, kb) (((row) << 7) + ((kb) ^ (((row) & 7) << 4)))

// ---------------- LayerNorm -> e (gate & update), f32 + fp16 copies ----------------
__global__ __launch_bounds__(256) void k_ln_e(
    const float* __restrict__ ne, const float* __restrict__ te,
    const float* __restrict__ gg, const float* __restrict__ gb,
    const float* __restrict__ ug, const float* __restrict__ ub,
    float* __restrict__ eg, float* __restrict__ eu,
    f16* __restrict__ egh, f16* __restrict__ euh) {
  int node = blockIdx.x * 4 + (threadIdx.x >> 6);
  int d = threadIdx.x & 63;
  float v = ne[node * DD + d] + te[d];
  float s = v;
  #pragma unroll
  for (int m = 1; m < 64; m <<= 1) s += __shfl_xor(s, m, 64);
  float mu = s * (1.f / 64.f);
  float df = v - mu;
  float q = df * df;
  #pragma unroll
  for (int m = 1; m < 64; m <<= 1) q += __shfl_xor(q, m, 64);
  float rs = rsqrtf(q * (1.f / 64.f) + 1e-12f);
  float base = df * rs;
  float a = base * gg[d] + gb[d];
  float b = base * ug[d] + ub[d];
  eg[node * DD + d] = a; egh[node * DD + d] = (f16)a;
  eu[node * DD + d] = b; euh[node * DD + d] = (f16)b;
}

// ---------------- bias = e @ bpool (f32) ----------------
__global__ void k_bias(const float* __restrict__ e, const float* __restrict__ bpool,
                       float* __restrict__ bias, int O) {
  __shared__ float es[64];
  int n = blockIdx.x;
  int o = threadIdx.x;
  if (o < 64) es[o] = e[n * DD + o];
  __syncthreads();
  float acc = 0.f;
  #pragma unroll 8
  for (int d = 0; d < 64; ++d) acc += es[d] * bpool[d * O + o];
  bias[(size_t)n * O + o] = acc;
}

// ---------------- wpool (d,ki,o) f32 -> wpool_t (o*KI+ki, d) fp16 ----------------
__global__ __launch_bounds__(256) void k_wpool_t(const float* __restrict__ wpool,
                                                 f16* __restrict__ wt, int O) {
  __shared__ float tile[64][17];
  int ki = blockIdx.x;
  int o0 = blockIdx.y * 16;
  int t = threadIdx.x;
  #pragma unroll
  for (int i = 0; i < 4; ++i) {
    int e2 = i * 256 + t;
    int d = e2 >> 4, o = e2 & 15;
    tile[d][o] = wpool[((size_t)d * KI + ki) * O + o0 + o];
  }
  __syncthreads();
  #pragma unroll
  for (int i = 0; i < 4; ++i) {
    int e2 = i * 256 + t;
    int o = e2 >> 6, d = e2 & 63;
    wt[((size_t)(o0 + o) * KI + ki) * DD + d] = (f16)tile[d][o];
  }
}

// ---------------- build cm[b][c][m] AND xg[m][b][c] (c<96) in one pass ----------------
__global__ __launch_bounds__(256) void k_build_inp(const float* __restrict__ x,
                                                   const float* __restrict__ st,
                                                   f16* __restrict__ cm,
                                                   f16* __restrict__ xg) {
  __shared__ f16 tile[96][66];
  int mb = blockIdx.x * 64;
  int b = blockIdx.y;
  int t = threadIdx.x;
  #pragma unroll
  for (int i = 0; i < 24; ++i) {
    int e2 = i * 256 + t;  // 0..6143
    int m = e2 / 96, c = e2 % 96;
    float v = (c < CINC) ? x[((size_t)b * NN + mb + m) * CINC + c]
                         : st[((size_t)b * NN + mb + m) * HH + c - CINC];
    f16 h = (f16)v;
    tile[c][m] = h;
    xg[((size_t)(mb + m) * BB + b) * KI + c] = h;
  }
  __syncthreads();
  #pragma unroll
  for (int i = 0; i < 24; ++i) {
    int e2 = i * 256 + t;
    int c = e2 >> 6, m = e2 & 63;
    cm[((size_t)b * C1 + c) * NN + mb + m] = tile[c][m];
  }
}

// ---------------- zs[b][m][o] -> cand_cm[b][32+o][m] ----------------
__global__ __launch_bounds__(256) void k_transpose_zs(const f16* __restrict__ zs,
                                                      f16* __restrict__ cm) {
  __shared__ f16 tile[64][66];
  int mb = blockIdx.x * 64;
  int b = blockIdx.y;
  int t = threadIdx.x;
  #pragma unroll
  for (int i = 0; i < 16; ++i) {
    int e2 = i * 256 + t;
    int m = e2 >> 6, o = e2 & 63;
    tile[o][m] = zs[((size_t)b * NN + mb + m) * HH + o];
  }
  __syncthreads();
  #pragma unroll
  for (int i = 0; i < 16; ++i) {
    int e2 = i * 256 + t;
    int o = e2 >> 6, m = e2 & 63;
    cm[((size_t)b * C1 + CINC + o) * NN + mb + m] = tile[o][m];
  }
}

// ---------------- S = e @ e^T  (f32, 32x32 tiles) ----------------
__global__ __launch_bounds__(256) void k_scores(const float* __restrict__ e,
                                                float* __restrict__ S) {
  __shared__ float er[32][65];
  __shared__ float ec[32][65];
  int rb = blockIdx.y * 32, cbb = blockIdx.x * 32;
  int t = threadIdx.x;
  {
    int row = t >> 3;
    int d0 = (t & 7) * 8;
    const float* pr = &e[(size_t)(rb + row) * DD + d0];
    const float* pc = &e[(size_t)(cbb + row) * DD + d0];
    #pragma unroll
    for (int j = 0; j < 8; ++j) { er[row][d0 + j] = pr[j]; ec[row][d0 + j] = pc[j]; }
  }
  __syncthreads();
  int r = t >> 5;   // 0..7
  int c = t & 31;
  float a0 = 0.f, a1 = 0.f, a2 = 0.f, a3 = 0.f;
  #pragma unroll 8
  for (int d = 0; d < 64; ++d) {
    float vc = ec[c][d];
    a0 += er[r][d] * vc;
    a1 += er[r + 8][d] * vc;
    a2 += er[r + 16][d] * vc;
    a3 += er[r + 24][d] * vc;
  }
  S[(size_t)(rb + r) * NN + cbb + c] = a0;
  S[(size_t)(rb + r + 8) * NN + cbb + c] = a1;
  S[(size_t)(rb + r + 16) * NN + cbb + c] = a2;
  S[(size_t)(rb + r + 24) * NN + cbb + c] = a3;
}

// ---------------- row softmax -> adj fp16 ----------------
__global__ __launch_bounds__(256) void k_softmax(const float* __restrict__ S,
                                                 f16* __restrict__ adj) {
  int n = blockIdx.x;
  int t = threadIdx.x;
  const float* row = S + (size_t)n * NN;
  float v[8];
  float mx = -3.0e38f;
  #pragma unroll
  for (int i = 0; i < 8; ++i) { v[i] = row[t + i * 256]; mx = fmaxf(mx, v[i]); }
  #pragma unroll
  for (int m = 1; m < 64; m <<= 1) mx = fmaxf(mx, __shfl_xor(mx, m, 64));
  __shared__ float redm[4];
  if ((t & 63) == 0) redm[t >> 6] = mx;
  __syncthreads();
  mx = fmaxf(fmaxf(redm[0], redm[1]), fmaxf(redm[2], redm[3]));
  float s = 0.f;
  #pragma unroll
  for (int i = 0; i < 8; ++i) { v[i] = expf(v[i] - mx); s += v[i]; }
  #pragma unroll
  for (int m = 1; m < 64; m <<= 1) s += __shfl_xor(s, m, 64);
  __shared__ float reds[4];
  if ((t & 63) == 0) reds[t >> 6] = s;
  __syncthreads();
  s = reds[0] + reds[1] + reds[2] + reds[3];
  float inv = 1.f / s;
  #pragma unroll
  for (int i = 0; i < 8; ++i) adj[(size_t)n * NN + t + i * 256] = (f16)(v[i] * inv);
}

// ---------------- xa: xg[n][b][96+l] = adj(n,m) @ cm(b*96+l, m)^T ----------------
// 128x96 tile, BK=64, double-buffered global_load_lds, one barrier per K-tile.
#define BM 128
#define BN 96

__global__ __launch_bounds__(256, 2) void k_gemm_xa(const f16* __restrict__ A,
                                                    const f16* __restrict__ Bm,
                                                    f16* __restrict__ xg) {
  __shared__ f16 Al[2][BM * 64];
  __shared__ f16 Bl[2][BN * 64];
  const int nb = blockIdx.x * BM;
  const int by = blockIdx.y;        // one batch per y-tile (BN == 96)
  const int cb = by * BN;
  const int tid = threadIdx.x;
  const int w = tid >> 6, lane = tid & 63;
  const int wr = (w >> 1) * 64, wc = (w & 1) * 48;
  const int fr = lane & 15, fq = lane >> 4;

  const int arow = tid >> 3;                               // 0..31
  const int acolb = ((tid & 7) * 16) ^ ((arow & 7) << 4);  // pre-swizzled, j-invariant
  const char* asrc = (const char*)A + (size_t)(nb + arow) * (NN * 2) + acolb;
  const char* bsrc = (const char*)Bm + (size_t)(cb + arow) * (NN * 2) + acolb;

  auto stage = [&](int buf, int kt) {
    const size_t ko = (size_t)kt * 2;
    char* ad = (char*)&Al[buf][0] + (w << 10);
    char* bd = (char*)&Bl[buf][0] + (w << 10);
    #pragma unroll
    for (int j = 0; j < 4; ++j)
      gl_lds16(asrc + ko + (size_t)j * 32 * (NN * 2), ad + j * 4096);
    #pragma unroll
    for (int j = 0; j < 3; ++j)
      gl_lds16(bsrc + ko + (size_t)j * 32 * (NN * 2), bd + j * 4096);
  };

  f32x4 acc[4][3] = {};
  stage(0, 0);
  for (int kt = 0; kt < NN; kt += 64) {
    const int cur = (kt >> 6) & 1;
    __syncthreads();                       // drains stage(cur) + prior ds_reads
    if (kt + 64 < NN) stage(cur ^ 1, kt + 64);
    const char* Ab = (const char*)&Al[cur][0];
    const char* Bb = (const char*)&Bl[cur][0];
    #pragma unroll
    for (int k0 = 0; k0 < 2; ++k0) {
      const int kb = k0 * 64 + fq * 16;
      half8 af[4], bf[3];
      #pragma unroll
      for (int mt = 0; mt < 4; ++mt)
        af[mt] = *(const half8*)(Ab + SWZ(wr + mt * 16 + fr, kb));
      #pragma unroll
      for (int nt = 0; nt < 3; ++nt)
        bf[nt] = *(const half8*)(Bb + SWZ(wc + nt * 16 + fr, kb));
      #pragma unroll
      for (int mt = 0; mt < 4; ++mt)
        #pragma unroll
        for (int nt = 0; nt < 3; ++nt)
          acc[mt][nt] = mfma16(af[mt], bf[nt], acc[mt][nt]);
    }
  }
  #pragma unroll
  for (int mt = 0; mt < 4; ++mt)
    #pragma unroll
    for (int nt = 0; nt < 3; ++nt)
      #pragma unroll
      for (int r = 0; r < 4; ++r) {
        int n = nb + wr + mt * 16 + fq * 4 + r;
        int l = wc + nt * 16 + fr;         // 0..95
        xg[((size_t)n * BB + by) * KI + 96 + l] = (f16)acc[mt][nt][r];
      }
}

// ---------------- W(all nodes, 64-o chunk): W[n][o'][ki] = e(n,:) . wt(o'*KI+ki, :) ----------------
// GEMM M=2048, N=12288, K=64. 128x128 tiles, LDS-staged, swizzled.
__global__ __launch_bounds__(256) void k_gemm_w2(const f16* __restrict__ A,
                                                 const f16* __restrict__ B,
                                                 f16* __restrict__ W) {
  __shared__ f16 Al[128 * 64];
  __shared__ f16 Bl[128 * 64];
  const int cb = blockIdx.x * 128;
  const int nb = blockIdx.y * 128;
  const int tid = threadIdx.x;
  const int w = tid >> 6, lane = tid & 63;
  const int wr = (w >> 1) * 64, wc = (w & 1) * 64;
  const int fr = lane & 15, fq = lane >> 4;
  const int arow = tid >> 3;
  const int acolb = ((tid & 7) * 16) ^ ((arow & 7) << 4);
  const char* asrc = (const char*)A + (size_t)(nb + arow) * 128 + acolb;
  const char* bsrc = (const char*)B + (size_t)(cb + arow) * 128 + acolb;
  char* ad = (char*)Al + (w << 10);
  char* bd = (char*)Bl + (w << 10);
  #pragma unroll
  for (int j = 0; j < 4; ++j) gl_lds16(asrc + (size_t)j * 32 * 128, ad + j * 4096);
  #pragma unroll
  for (int j = 0; j < 4; ++j) gl_lds16(bsrc + (size_t)j * 32 * 128, bd + j * 4096);
  __syncthreads();
  f32x4 acc[4][4] = {};
  #pragma unroll
  for (int k0 = 0; k0 < 2; ++k0) {
    const int kb = k0 * 64 + fq * 16;
    half8 af[4], bf[4];
    #pragma unroll
    for (int mt = 0; mt < 4; ++mt)
      af[mt] = *(const half8*)((const char*)Al + SWZ(wr + mt * 16 + fr, kb));
    #pragma unroll
    for (int nt = 0; nt < 4; ++nt)
      bf[nt] = *(const half8*)((const char*)Bl + SWZ(wc + nt * 16 + fr, kb));
    #pragma unroll
    for (int mt = 0; mt < 4; ++mt)
      #pragma unroll
      for (int nt = 0; nt < 4; ++nt)
        acc[mt][nt] = mfma16(af[mt], bf[nt], acc[mt][nt]);
  }
  #pragma unroll
  for (int mt = 0; mt < 4; ++mt)
    #pragma unroll
    for (int nt = 0; nt < 4; ++nt)
      #pragma unroll
      for (int r = 0; r < 4; ++r) {
        int n = nb + wr + mt * 16 + fq * 4 + r;
        int c = cb + wc + nt * 16 + fr;
        W[(size_t)n * WCOLS + c] = (f16)acc[mt][nt][r];
      }
}

// ---------------- apply: out(b,n,o') = xg(n,b,:) . W[n](o',:) + bias, + epilogues ----------------
// MODE 0: gate-r (writes rbuf f16); MODE 1: gate-z (writes xg z-slice + zs);
// MODE 2: update (writes final out).
template <int MODE>
__global__ __launch_bounds__(256) void k_apply2(
    const f16* __restrict__ xg, const f16* __restrict__ W,
    const float* __restrict__ bias, int bstride,
    const float* __restrict__ state,
    f16* xgw, f16* __restrict__ zs, f16* __restrict__ rbuf,
    float* __restrict__ outp) {
  const int n = blockIdx.x;
  const int lane = threadIdx.x & 63, w = threadIdx.x >> 6;
  const int fr = lane & 15, fq = lane >> 4;
  half8 af[2][6];
  #pragma unroll
  for (int mt = 0; mt < 2; ++mt) {
    const f16* arow = xg + ((size_t)n * BB + mt * 16 + fr) * KI;
    #pragma unroll
    for (int ks = 0; ks < 6; ++ks)
      af[mt][ks] = *(const half8*)&arow[ks * 32 + fq * 8];
  }
  if (MODE == 1) __syncthreads();  // all A reads before z-slice writes to xg
  const f16* wrow = W + (size_t)n * WCOLS + (size_t)(w * 16 + fr) * KI;
  f32x4 acc[2] = {};
  #pragma unroll
  for (int ks = 0; ks < 6; ++ks) {
    half8 bf = *(const half8*)&wrow[ks * 32 + fq * 8];
    acc[0] = mfma16(af[0][ks], bf, acc[0]);
    acc[1] = mfma16(af[1][ks], bf, acc[1]);
  }
  const int o = w * 16 + fr;
  const float bs = bias[(size_t)n * bstride + o];
  #pragma unroll
  for (int mt = 0; mt < 2; ++mt)
    #pragma unroll
    for (int r = 0; r < 4; ++r) {
      int b = mt * 16 + fq * 4 + r;
      float val = acc[mt][r] + bs;
      size_t bno = ((size_t)b * NN + n) * HH + o;
      if (MODE == 0) {
        rbuf[bno] = (f16)(1.f / (1.f + expf(-val)));
      } else if (MODE == 1) {
        float zst = (1.f / (1.f + expf(-val))) * state[bno];
        xgw[((size_t)n * BB + b) * KI + CINC + o] = (f16)zst;
        zs[bno] = (f16)zst;
      } else {
        float hc = tanhf(val);
        float rr = (float)rbuf[bno];
        outp[bno] = rr * state[bno] + (1.f - rr) * hc;
      }
    }
}

extern "C" void kernel_launch(void* const* d_in, const int* in_sizes, int n_in,
                              void* d_out, int out_size, void* d_ws, size_t ws_size,
                              hipStream_t stream) {
  const float* x   = (const float*)d_in[0];
  const float* st  = (const float*)d_in[1];
  const float* ne  = (const float*)d_in[2];
  const float* te  = (const float*)d_in[3];
  const float* gwp = (const float*)d_in[4];
  const float* gbp = (const float*)d_in[5];
  const float* gg  = (const float*)d_in[6];
  const float* gb  = (const float*)d_in[7];
  const float* uwp = (const float*)d_in[8];
  const float* ubp = (const float*)d_in[9];
  const float* ug  = (const float*)d_in[10];
  const float* ub  = (const float*)d_in[11];
  float* out = (float*)d_out;

  char* wsb = (char*)d_ws;
  size_t off = 0;
  auto alloc = [&](size_t bytes) {
    char* p = wsb + off;
    off = (off + bytes + 255) & ~(size_t)255;
    return p;
  };
  float* e_g   = (float*)alloc((size_t)NN * DD * 4);
  float* e_u   = (float*)alloc((size_t)NN * DD * 4);
  f16*   egh   = (f16*)  alloc((size_t)NN * DD * 2);
  f16*   euh   = (f16*)  alloc((size_t)NN * DD * 2);
  float* biasg = (float*)alloc((size_t)NN * OG * 4);
  float* biasu = (float*)alloc((size_t)NN * OU * 4);
  f16*   wtg   = (f16*)  alloc((size_t)OG * KI * DD * 2);
  f16*   wtu   = (f16*)  alloc((size_t)OU * KI * DD * 2);
  f16*   xg    = (f16*)  alloc((size_t)NN * BB * KI * 2);   // 24 MB
  f16*   cm    = (f16*)  alloc((size_t)BB * C1 * NN * 2);   // 12 MB
  f16*   zs    = (f16*)  alloc((size_t)BB * NN * HH * 2);   //  8 MB
  f16*   rbuf  = (f16*)  alloc((size_t)BB * NN * HH * 2);   //  8 MB
  char*  Wreg  =         alloc((size_t)NN * WCOLS * 2);     // 48 MB; aliases S+adj
  float* S     = (float*)Wreg;                               // 16 MB
  f16*   adj   = (f16*)(Wreg + (size_t)NN * NN * 4);         //  8 MB
  f16*   W     = (f16*)Wreg;
  (void)ws_size; (void)in_sizes; (void)n_in; (void)out_size;

  hipLaunchKernelGGL(k_ln_e, dim3(NN / 4), dim3(256), 0, stream,
                     ne, te, gg, gb, ug, ub, e_g, e_u, egh, euh);
  hipLaunchKernelGGL(k_bias, dim3(NN), dim3(OG), 0, stream, e_g, gbp, biasg, OG);
  hipLaunchKernelGGL(k_bias, dim3(NN), dim3(OU), 0, stream, e_u, ubp, biasu, OU);
  hipLaunchKernelGGL(k_wpool_t, dim3(KI, OG / 16), dim3(256), 0, stream, gwp, wtg, OG);
  hipLaunchKernelGGL(k_wpool_t, dim3(KI, OU / 16), dim3(256), 0, stream, uwp, wtu, OU);
  hipLaunchKernelGGL(k_build_inp, dim3(NN / 64, BB), dim3(256), 0, stream, x, st, cm, xg);

  // ---- gate GCN ----
  hipLaunchKernelGGL(k_scores, dim3(NN / 32, NN / 32), dim3(256), 0, stream, e_g, S);
  hipLaunchKernelGGL(k_softmax, dim3(NN), dim3(256), 0, stream, S, adj);
  hipLaunchKernelGGL(k_gemm_xa, dim3(NN / BM, BB), dim3(256), 0, stream, adj, cm, xg);
  // r-half first (o in [64,128)): reads xg before the z-slice is overwritten
  hipLaunchKernelGGL(k_gemm_w2, dim3(WCOLS / 128, NN / 128), dim3(256), 0, stream,
                     egh, wtg + (size_t)WCOLS * DD, W);
  hipLaunchKernelGGL((k_apply2<0>), dim3(NN), dim3(256), 0, stream,
                     xg, W, biasg + 64, OG, st, (f16*)nullptr, (f16*)nullptr, rbuf, (float*)nullptr);
  // z-half (o in [0,64))
  hipLaunchKernelGGL(k_gemm_w2, dim3(WCOLS / 128, NN / 128), dim3(256), 0, stream,
                     egh, wtg, W);
  hipLaunchKernelGGL((k_apply2<1>), dim3(NN), dim3(256), 0, stream,
                     xg, W, biasg, OG, st, xg, zs, (f16*)nullptr, (float*)nullptr);
  hipLaunchKernelGGL(k_transpose_zs, dim3(NN / 64, BB), dim3(256), 0, stream, zs, cm);

  // ---- update GCN ----
  hipLaunchKernelGGL(k_scores, dim3(NN / 32, NN / 32), dim3(256), 0, stream, e_u, S);
  hipLaunchKernelGGL(k_softmax, dim3(NN), dim3(256), 0, stream, S, adj);
  hipLaunchKernelGGL(k_gemm_xa, dim3(NN / BM, BB), dim3(256), 0, stream, adj, cm, xg);
  hipLaunchKernelGGL(k_gemm_w2, dim3(WCOLS / 128, NN / 128), dim3(256), 0, stream,
                     euh, wtu, W);
  hipLaunchKernelGGL((k_apply2<2>), dim3(NN), dim3(256), 0, stream,
                     xg, W, biasu, OU, st, (f16*)nullptr, (f16*)nullptr, rbuf, out);
}

// Round 4
// 266.965 us; speedup vs baseline: 1.6821x; 1.0491x over previous
//
#include <hip/hip_runtime.h>

typedef _Float16 f16;
typedef _Float16 half8 __attribute__((ext_vector_type(8)));
typedef float f32x4 __attribute__((ext_vector_type(4)));

#define NN 2048
#define BB 32
#define CINC 32
#define HH 64
#define DD 64
#define C1 96      // CIN + H
#define KI 192     // 2 * C1
#define OG 128
#define OU 64
#define WCOLS 12288  // 64 * KI, per o-chunk of 64

__device__ __forceinline__ f32x4 mfma16(half8 a, half8 b, f32x4 c) {
  return __builtin_amdgcn_mfma_f32_16x16x32_f16(a, b, c, 0, 0, 0);
}

typedef __attribute__((address_space(1))) const void* gas_t;
typedef __attribute__((address_space(3))) void* las_t;
__device__ __forceinline__ void gl_lds16(const void* g, void* l) {
  __builtin_amdgcn_global_load_lds((gas_t)g, (las_t)l, 16, 0, 0);
}

// XOR swizzle for 128B-row LDS tiles (rule #21: pre-swizzled source + swizzled read)
#define SWZ(row, kb) (((row) << 7) + ((kb) ^ (((row) & 7) << 4)))

// ---------------- LayerNorm -> e (gate & update), f32 + fp16 copies ----------------
__global__ __launch_bounds__(256) void k_ln_e(
    const float* __restrict__ ne, const float* __restrict__ te,
    const float* __restrict__ gg, const float* __restrict__ gb,
    const float* __restrict__ ug, const float* __restrict__ ub,
    float* __restrict__ eg, float* __restrict__ eu,
    f16* __restrict__ egh, f16* __restrict__ euh) {
  int node = blockIdx.x * 4 + (threadIdx.x >> 6);
  int d = threadIdx.x & 63;
  float v = ne[node * DD + d] + te[d];
  float s = v;
  #pragma unroll
  for (int m = 1; m < 64; m <<= 1) s += __shfl_xor(s, m, 64);
  float mu = s * (1.f / 64.f);
  float df = v - mu;
  float q = df * df;
  #pragma unroll
  for (int m = 1; m < 64; m <<= 1) q += __shfl_xor(q, m, 64);
  float rs = rsqrtf(q * (1.f / 64.f) + 1e-12f);
  float base = df * rs;
  float a = base * gg[d] + gb[d];
  float b = base * ug[d] + ub[d];
  eg[node * DD + d] = a; egh[node * DD + d] = (f16)a;
  eu[node * DD + d] = b; euh[node * DD + d] = (f16)b;
}

// ---------------- both biases in one launch: threads 0..127 gate, 128..191 update ----------------
__global__ __launch_bounds__(192) void k_bias2(
    const float* __restrict__ eg, const float* __restrict__ eu,
    const float* __restrict__ gbp, const float* __restrict__ ubp,
    float* __restrict__ biasg, float* __restrict__ biasu) {
  __shared__ float es[2][64];
  int n = blockIdx.x;
  int t = threadIdx.x;
  if (t < 64) es[0][t] = eg[n * DD + t];
  else if (t < 128) es[1][t - 64] = eu[n * DD + t - 64];
  __syncthreads();
  if (t < 128) {
    float acc = 0.f;
    #pragma unroll 8
    for (int d = 0; d < 64; ++d) acc += es[0][d] * gbp[d * OG + t];
    biasg[(size_t)n * OG + t] = acc;
  } else {
    int o = t - 128;
    float acc = 0.f;
    #pragma unroll 8
    for (int d = 0; d < 64; ++d) acc += es[1][d] * ubp[d * OU + o];
    biasu[(size_t)n * OU + o] = acc;
  }
}

// ---------------- wpool (d,ki,o) f32 -> wpool_t (o*KI+ki, d) fp16 ; z selects gate/update ----------
__global__ __launch_bounds__(256) void k_wpool_t(const float* __restrict__ gwp,
                                                 const float* __restrict__ uwp,
                                                 f16* __restrict__ wtg,
                                                 f16* __restrict__ wtu) {
  const int upd = blockIdx.z;
  if (upd && blockIdx.y >= OU / 16) return;
  const float* wpool = upd ? uwp : gwp;
  f16* wt = upd ? wtu : wtg;
  const int O = upd ? OU : OG;
  __shared__ float tile[64][17];
  int ki = blockIdx.x;
  int o0 = blockIdx.y * 16;
  int t = threadIdx.x;
  #pragma unroll
  for (int i = 0; i < 4; ++i) {
    int e2 = i * 256 + t;
    int d = e2 >> 4, o = e2 & 15;
    tile[d][o] = wpool[((size_t)d * KI + ki) * O + o0 + o];
  }
  __syncthreads();
  #pragma unroll
  for (int i = 0; i < 4; ++i) {
    int e2 = i * 256 + t;
    int o = e2 >> 6, d = e2 & 63;
    wt[((size_t)(o0 + o) * KI + ki) * DD + d] = (f16)tile[d][o];
  }
}

// ------- build cm[b][c][m], xg[m][b][c] (c<96), sth[b][m][o] f16 in one pass -------
__global__ __launch_bounds__(256) void k_build_inp(const float* __restrict__ x,
                                                   const float* __restrict__ st,
                                                   f16* __restrict__ cm,
                                                   f16* __restrict__ xg,
                                                   f16* __restrict__ sth) {
  __shared__ f16 tile[96][66];
  int mb = blockIdx.x * 64;
  int b = blockIdx.y;
  int t = threadIdx.x;
  #pragma unroll
  for (int i = 0; i < 24; ++i) {
    int e2 = i * 256 + t;  // 0..6143
    int m = e2 / 96, c = e2 % 96;
    float v = (c < CINC) ? x[((size_t)b * NN + mb + m) * CINC + c]
                         : st[((size_t)b * NN + mb + m) * HH + c - CINC];
    f16 h = (f16)v;
    tile[c][m] = h;
    xg[((size_t)(mb + m) * BB + b) * KI + c] = h;
    if (c >= CINC) sth[((size_t)b * NN + mb + m) * HH + c - CINC] = h;
  }
  __syncthreads();
  #pragma unroll
  for (int i = 0; i < 24; ++i) {
    int e2 = i * 256 + t;
    int c = e2 >> 6, m = e2 & 63;
    cm[((size_t)b * C1 + c) * NN + mb + m] = tile[c][m];
  }
}

// ---------------- zs[b][m][o] -> cand_cm[b][32+o][m] ----------------
__global__ __launch_bounds__(256) void k_transpose_zs(const f16* __restrict__ zs,
                                                      f16* __restrict__ cm) {
  __shared__ f16 tile[64][66];
  int mb = blockIdx.x * 64;
  int b = blockIdx.y;
  int t = threadIdx.x;
  #pragma unroll
  for (int i = 0; i < 16; ++i) {
    int e2 = i * 256 + t;
    int m = e2 >> 6, o = e2 & 63;
    tile[o][m] = zs[((size_t)b * NN + mb + m) * HH + o];
  }
  __syncthreads();
  #pragma unroll
  for (int i = 0; i < 16; ++i) {
    int e2 = i * 256 + t;
    int o = e2 >> 6, m = e2 & 63;
    cm[((size_t)b * C1 + CINC + o) * NN + mb + m] = tile[o][m];
  }
}

// ---------------- S = e @ e^T  (f32, 32x32 tiles) ----------------
__global__ __launch_bounds__(256) void k_scores(const float* __restrict__ e,
                                                float* __restrict__ S) {
  __shared__ float er[32][65];
  __shared__ float ec[32][65];
  int rb = blockIdx.y * 32, cbb = blockIdx.x * 32;
  int t = threadIdx.x;
  {
    int row = t >> 3;
    int d0 = (t & 7) * 8;
    const float* pr = &e[(size_t)(rb + row) * DD + d0];
    const float* pc = &e[(size_t)(cbb + row) * DD + d0];
    #pragma unroll
    for (int j = 0; j < 8; ++j) { er[row][d0 + j] = pr[j]; ec[row][d0 + j] = pc[j]; }
  }
  __syncthreads();
  int r = t >> 5;   // 0..7
  int c = t & 31;
  float a0 = 0.f, a1 = 0.f, a2 = 0.f, a3 = 0.f;
  #pragma unroll 8
  for (int d = 0; d < 64; ++d) {
    float vc = ec[c][d];
    a0 += er[r][d] * vc;
    a1 += er[r + 8][d] * vc;
    a2 += er[r + 16][d] * vc;
    a3 += er[r + 24][d] * vc;
  }
  S[(size_t)(rb + r) * NN + cbb + c] = a0;
  S[(size_t)(rb + r + 8) * NN + cbb + c] = a1;
  S[(size_t)(rb + r + 16) * NN + cbb + c] = a2;
  S[(size_t)(rb + r + 24) * NN + cbb + c] = a3;
}

// ---------------- row softmax -> adj fp16 ----------------
__global__ __launch_bounds__(256) void k_softmax(const float* __restrict__ S,
                                                 f16* __restrict__ adj) {
  int n = blockIdx.x;
  int t = threadIdx.x;
  const float* row = S + (size_t)n * NN;
  float v[8];
  float mx = -3.0e38f;
  #pragma unroll
  for (int i = 0; i < 8; ++i) { v[i] = row[t + i * 256]; mx = fmaxf(mx, v[i]); }
  #pragma unroll
  for (int m = 1; m < 64; m <<= 1) mx = fmaxf(mx, __shfl_xor(mx, m, 64));
  __shared__ float redm[4];
  if ((t & 63) == 0) redm[t >> 6] = mx;
  __syncthreads();
  mx = fmaxf(fmaxf(redm[0], redm[1]), fmaxf(redm[2], redm[3]));
  float s = 0.f;
  #pragma unroll
  for (int i = 0; i < 8; ++i) { v[i] = expf(v[i] - mx); s += v[i]; }
  #pragma unroll
  for (int m = 1; m < 64; m <<= 1) s += __shfl_xor(s, m, 64);
  __shared__ float reds[4];
  if ((t & 63) == 0) reds[t >> 6] = s;
  __syncthreads();
  s = reds[0] + reds[1] + reds[2] + reds[3];
  float inv = 1.f / s;
  #pragma unroll
  for (int i = 0; i < 8; ++i) adj[(size_t)n * NN + t + i * 256] = (f16)(v[i] * inv);
}

// ---------------- xa: xg[n][b][96+l] = adj(n,m) @ cm(b*96+l, m)^T ----------------
// 64x96 tile, BK=64, dbuf + counted-vmcnt pipeline (T4), 4 blocks/CU.
#define BM 64
#define BN 96

__global__ __launch_bounds__(256, 4) void k_gemm_xa(const f16* __restrict__ A,
                                                    const f16* __restrict__ Bm,
                                                    f16* __restrict__ xg) {
  __shared__ f16 Al[2][BM * 64];
  __shared__ f16 Bl[2][BN * 64];
  const int nb = blockIdx.x * BM;
  const int by = blockIdx.y;        // one batch per y-tile (BN == 96)
  const int cb = by * BN;
  const int tid = threadIdx.x;
  const int w = tid >> 6, lane = tid & 63;
  const int wr = (w >> 1) * 32, wc = (w & 1) * 48;
  const int fr = lane & 15, fq = lane >> 4;

  const int arow = tid >> 3;                               // 0..31
  const int acolb = ((tid & 7) * 16) ^ ((arow & 7) << 4);  // pre-swizzled, j-invariant
  const char* asrc = (const char*)A + (size_t)(nb + arow) * (NN * 2) + acolb;
  const char* bsrc = (const char*)Bm + (size_t)(cb + arow) * (NN * 2) + acolb;

  auto stage = [&](int buf, int kt) {   // 5 x global_load_lds per wave
    const size_t ko = (size_t)kt * 2;
    char* ad = (char*)&Al[buf][0] + (w << 10);
    char* bd = (char*)&Bl[buf][0] + (w << 10);
    gl_lds16(asrc + ko, ad);
    gl_lds16(asrc + ko + (size_t)32 * (NN * 2), ad + 4096);
    gl_lds16(bsrc + ko, bd);
    gl_lds16(bsrc + ko + (size_t)32 * (NN * 2), bd + 4096);
    gl_lds16(bsrc + ko + (size_t)64 * (NN * 2), bd + 8192);
  };

  f32x4 acc[2][3] = {};
  stage(0, 0);
  for (int kt = 0; kt < NN; kt += 64) {
    const int cur = (kt >> 6) & 1;
    if (kt + 64 < NN) {
      stage(cur ^ 1, kt + 64);
      asm volatile("s_waitcnt vmcnt(5)" ::: "memory");   // my stage(cur) landed
    } else {
      asm volatile("s_waitcnt vmcnt(0)" ::: "memory");
    }
    __builtin_amdgcn_sched_barrier(0);
    __builtin_amdgcn_s_barrier();                         // A: buf[cur] ready (all waves)
    const char* Ab = (const char*)&Al[cur][0];
    const char* Bb = (const char*)&Bl[cur][0];
    half8 af[2][2], bf[2][3];
    #pragma unroll
    for (int k0 = 0; k0 < 2; ++k0) {
      const int kb = k0 * 64 + fq * 16;
      #pragma unroll
      for (int mt = 0; mt < 2; ++mt)
        af[k0][mt] = *(const half8*)(Ab + SWZ(wr + mt * 16 + fr, kb));
      #pragma unroll
      for (int nt = 0; nt < 3; ++nt)
        bf[k0][nt] = *(const half8*)(Bb + SWZ(wc + nt * 16 + fr, kb));
    }
    asm volatile("s_waitcnt lgkmcnt(0)" ::: "memory");    // my reads of buf[cur] done
    __builtin_amdgcn_sched_barrier(0);
    __builtin_amdgcn_s_barrier();                         // B: release buf[cur] for restage
    #pragma unroll
    for (int k0 = 0; k0 < 2; ++k0)
      #pragma unroll
      for (int mt = 0; mt < 2; ++mt)
        #pragma unroll
        for (int nt = 0; nt < 3; ++nt)
          acc[mt][nt] = mfma16(af[k0][mt], bf[k0][nt], acc[mt][nt]);
  }
  #pragma unroll
  for (int mt = 0; mt < 2; ++mt)
    #pragma unroll
    for (int nt = 0; nt < 3; ++nt)
      #pragma unroll
      for (int r = 0; r < 4; ++r) {
        int n = nb + wr + mt * 16 + fq * 4 + r;
        int l = wc + nt * 16 + fr;         // 0..95
        xg[((size_t)n * BB + by) * KI + 96 + l] = (f16)acc[mt][nt][r];
      }
}

// ---------------- W(all nodes, 64-o chunk): W[n][o'][ki] = e(n,:) . wt(o'*KI+ki, :) ----------------
// GEMM M=2048, N=12288, K=64. 128x128 tiles, LDS-staged, swizzled.
__global__ __launch_bounds__(256) void k_gemm_w2(const f16* __restrict__ A,
                                                 const f16* __restrict__ B,
                                                 f16* __restrict__ W) {
  __shared__ f16 Al[128 * 64];
  __shared__ f16 Bl[128 * 64];
  const int cb = blockIdx.x * 128;
  const int nb = blockIdx.y * 128;
  const int tid = threadIdx.x;
  const int w = tid >> 6, lane = tid & 63;
  const int wr = (w >> 1) * 64, wc = (w & 1) * 64;
  const int fr = lane & 15, fq = lane >> 4;
  const int arow = tid >> 3;
  const int acolb = ((tid & 7) * 16) ^ ((arow & 7) << 4);
  const char* asrc = (const char*)A + (size_t)(nb + arow) * 128 + acolb;
  const char* bsrc = (const char*)B + (size_t)(cb + arow) * 128 + acolb;
  char* ad = (char*)Al + (w << 10);
  char* bd = (char*)Bl + (w << 10);
  #pragma unroll
  for (int j = 0; j < 4; ++j) gl_lds16(asrc + (size_t)j * 32 * 128, ad + j * 4096);
  #pragma unroll
  for (int j = 0; j < 4; ++j) gl_lds16(bsrc + (size_t)j * 32 * 128, bd + j * 4096);
  __syncthreads();
  f32x4 acc[4][4] = {};
  #pragma unroll
  for (int k0 = 0; k0 < 2; ++k0) {
    const int kb = k0 * 64 + fq * 16;
    half8 af[4], bf[4];
    #pragma unroll
    for (int mt = 0; mt < 4; ++mt)
      af[mt] = *(const half8*)((const char*)Al + SWZ(wr + mt * 16 + fr, kb));
    #pragma unroll
    for (int nt = 0; nt < 4; ++nt)
      bf[nt] = *(const half8*)((const char*)Bl + SWZ(wc + nt * 16 + fr, kb));
    #pragma unroll
    for (int mt = 0; mt < 4; ++mt)
      #pragma unroll
      for (int nt = 0; nt < 4; ++nt)
        acc[mt][nt] = mfma16(af[mt], bf[nt], acc[mt][nt]);
  }
  #pragma unroll
  for (int mt = 0; mt < 4; ++mt)
    #pragma unroll
    for (int nt = 0; nt < 4; ++nt)
      #pragma unroll
      for (int r = 0; r < 4; ++r) {
        int n = nb + wr + mt * 16 + fq * 4 + r;
        int c = cb + wc + nt * 16 + fr;
        W[(size_t)n * WCOLS + c] = (f16)acc[mt][nt][r];
      }
}

// ---------------- apply: out(b,n,o') = xg(n,b,:) . W[n](o',:) + bias, + epilogues ----------------
// MODE 0: gate-r (writes rbuf f16); MODE 1: gate-z (writes xg z-slice + zs);
// MODE 2: update (writes final out).
template <int MODE>
__global__ __launch_bounds__(256) void k_apply2(
    const f16* __restrict__ xg, const f16* __restrict__ W,
    const float* __restrict__ bias, int bstride,
    const f16* __restrict__ sth,
    f16* xgw, f16* __restrict__ zs, f16* __restrict__ rbuf,
    float* __restrict__ outp) {
  const int n = blockIdx.x;
  const int lane = threadIdx.x & 63, w = threadIdx.x >> 6;
  const int fr = lane & 15, fq = lane >> 4;
  half8 af[2][6];
  #pragma unroll
  for (int mt = 0; mt < 2; ++mt) {
    const f16* arow = xg + ((size_t)n * BB + mt * 16 + fr) * KI;
    #pragma unroll
    for (int ks = 0; ks < 6; ++ks)
      af[mt][ks] = *(const half8*)&arow[ks * 32 + fq * 8];
  }
  if (MODE == 1) __syncthreads();  // all A reads before z-slice writes to xg
  const f16* wrow = W + (size_t)n * WCOLS + (size_t)(w * 16 + fr) * KI;
  f32x4 acc[2] = {};
  #pragma unroll
  for (int ks = 0; ks < 6; ++ks) {
    half8 bf = *(const half8*)&wrow[ks * 32 + fq * 8];
    acc[0] = mfma16(af[0][ks], bf, acc[0]);
    acc[1] = mfma16(af[1][ks], bf, acc[1]);
  }
  const int o = w * 16 + fr;
  const float bs = bias[(size_t)n * bstride + o];
  #pragma unroll
  for (int mt = 0; mt < 2; ++mt)
    #pragma unroll
    for (int r = 0; r < 4; ++r) {
      int b = mt * 16 + fq * 4 + r;
      float val = acc[mt][r] + bs;
      size_t bno = ((size_t)b * NN + n) * HH + o;
      if (MODE == 0) {
        rbuf[bno] = (f16)(1.f / (1.f + expf(-val)));
      } else if (MODE == 1) {
        float zst = (1.f / (1.f + expf(-val))) * (float)sth[bno];
        xgw[((size_t)n * BB + b) * KI + CINC + o] = (f16)zst;
        zs[bno] = (f16)zst;
      } else {
        float hc = tanhf(val);
        float rr = (float)rbuf[bno];
        outp[bno] = rr * (float)sth[bno] + (1.f - rr) * hc;
      }
    }
}

extern "C" void kernel_launch(void* const* d_in, const int* in_sizes, int n_in,
                              void* d_out, int out_size, void* d_ws, size_t ws_size,
                              hipStream_t stream) {
  const float* x   = (const float*)d_in[0];
  const float* st  = (const float*)d_in[1];
  const float* ne  = (const float*)d_in[2];
  const float* te  = (const float*)d_in[3];
  const float* gwp = (const float*)d_in[4];
  const float* gbp = (const float*)d_in[5];
  const float* gg  = (const float*)d_in[6];
  const float* gb  = (const float*)d_in[7];
  const float* uwp = (const float*)d_in[8];
  const float* ubp = (const float*)d_in[9];
  const float* ug  = (const float*)d_in[10];
  const float* ub  = (const float*)d_in[11];
  float* out = (float*)d_out;

  char* wsb = (char*)d_ws;
  size_t off = 0;
  auto alloc = [&](size_t bytes) {
    char* p = wsb + off;
    off = (off + bytes + 255) & ~(size_t)255;
    return p;
  };
  float* e_g   = (float*)alloc((size_t)NN * DD * 4);
  float* e_u   = (float*)alloc((size_t)NN * DD * 4);
  f16*   egh   = (f16*)  alloc((size_t)NN * DD * 2);
  f16*   euh   = (f16*)  alloc((size_t)NN * DD * 2);
  float* biasg = (float*)alloc((size_t)NN * OG * 4);
  float* biasu = (float*)alloc((size_t)NN * OU * 4);
  f16*   wtg   = (f16*)  alloc((size_t)OG * KI * DD * 2);
  f16*   wtu   = (f16*)  alloc((size_t)OU * KI * DD * 2);
  f16*   xg    = (f16*)  alloc((size_t)NN * BB * KI * 2);   // 24 MB
  f16*   cm    = (f16*)  alloc((size_t)BB * C1 * NN * 2);   // 12 MB
  f16*   zs    = (f16*)  alloc((size_t)BB * NN * HH * 2);   //  8 MB
  f16*   rbuf  = (f16*)  alloc((size_t)BB * NN * HH * 2);   //  8 MB
  f16*   sth   = (f16*)  alloc((size_t)BB * NN * HH * 2);   //  8 MB
  char*  Wreg  =         alloc((size_t)NN * WCOLS * 2);     // 48 MB; aliases S+adj
  float* S     = (float*)Wreg;                               // 16 MB
  f16*   adj   = (f16*)(Wreg + (size_t)NN * NN * 4);         //  8 MB
  f16*   W     = (f16*)Wreg;
  (void)ws_size; (void)in_sizes; (void)n_in; (void)out_size;

  hipLaunchKernelGGL(k_ln_e, dim3(NN / 4), dim3(256), 0, stream,
                     ne, te, gg, gb, ug, ub, e_g, e_u, egh, euh);
  hipLaunchKernelGGL(k_bias2, dim3(NN), dim3(192), 0, stream,
                     e_g, e_u, gbp, ubp, biasg, biasu);
  hipLaunchKernelGGL(k_wpool_t, dim3(KI, OG / 16, 2), dim3(256), 0, stream,
                     gwp, uwp, wtg, wtu);
  hipLaunchKernelGGL(k_build_inp, dim3(NN / 64, BB), dim3(256), 0, stream,
                     x, st, cm, xg, sth);

  // ---- gate GCN ----
  hipLaunchKernelGGL(k_scores, dim3(NN / 32, NN / 32), dim3(256), 0, stream, e_g, S);
  hipLaunchKernelGGL(k_softmax, dim3(NN), dim3(256), 0, stream, S, adj);
  hipLaunchKernelGGL(k_gemm_xa, dim3(NN / BM, BB), dim3(256), 0, stream, adj, cm, xg);
  // r-half first (o in [64,128)): reads xg before the z-slice is overwritten
  hipLaunchKernelGGL(k_gemm_w2, dim3(WCOLS / 128, NN / 128), dim3(256), 0, stream,
                     egh, wtg + (size_t)WCOLS * DD, W);
  hipLaunchKernelGGL((k_apply2<0>), dim3(NN), dim3(256), 0, stream,
                     xg, W, biasg + 64, OG, sth, (f16*)nullptr, (f16*)nullptr, rbuf, (float*)nullptr);
  // z-half (o in [0,64))
  hipLaunchKernelGGL(k_gemm_w2, dim3(WCOLS / 128, NN / 128), dim3(256), 0, stream,
                     egh, wtg, W);
  hipLaunchKernelGGL((k_apply2<1>), dim3(NN), dim3(256), 0, stream,
                     xg, W, biasg, OG, sth, xg, zs, (f16*)nullptr, (float*)nullptr);
  hipLaunchKernelGGL(k_transpose_zs, dim3(NN / 64, BB), dim3(256), 0, stream, zs, cm);

  // ---- update GCN ----
  hipLaunchKernelGGL(k_scores, dim3(NN / 32, NN / 32), dim3(256), 0, stream, e_u, S);
  hipLaunchKernelGGL(k_softmax, dim3(NN), dim3(256), 0, stream, S, adj);
  hipLaunchKernelGGL(k_gemm_xa, dim3(NN / BM, BB), dim3(256), 0, stream, adj, cm, xg);
  hipLaunchKernelGGL(k_gemm_w2, dim3(WCOLS / 128, NN / 128), dim3(256), 0, stream,
                     euh, wtu, W);
  hipLaunchKernelGGL((k_apply2<2>), dim3(NN), dim3(256), 0, stream,
                     xg, W, biasu, OU, sth, (f16*)nullptr, (f16*)nullptr, rbuf, out);
}

// Round 5
// 245.414 us; speedup vs baseline: 1.8298x; 1.0878x over previous
//
#include <hip/hip_runtime.h>

typedef _Float16 f16;
typedef _Float16 half8 __attribute__((ext_vector_type(8)));
typedef float f32x4 __attribute__((ext_vector_type(4)));

#define NN 2048
#define BB 32
#define CINC 32
#define HH 64
#define DD 64
#define C1 96      // CIN + H
#define KI 192     // 2 * C1
#define OG 128
#define OU 64
#define WCG 24576  // OG * KI
#define WCU 12288  // OU * KI

__device__ __forceinline__ f32x4 mfma16(half8 a, half8 b, f32x4 c) {
  return __builtin_amdgcn_mfma_f32_16x16x32_f16(a, b, c, 0, 0, 0);
}

typedef __attribute__((address_space(1))) const void* gas_t;
typedef __attribute__((address_space(3))) void* las_t;
__device__ __forceinline__ void gl_lds16(const void* g, void* l) {
  __builtin_amdgcn_global_load_lds((gas_t)g, (las_t)l, 16, 0, 0);
}

// XOR swizzle for 128B-row LDS tiles (rule #21: pre-swizzled source + swizzled read)
#define SWZ(row, kb) (((row) << 7) + ((kb) ^ (((row) & 7) << 4)))

// ------- LayerNorm -> e (gate & update) + both bias projections, one launch -------
__global__ __launch_bounds__(256) void k_ln_bias(
    const float* __restrict__ ne, const float* __restrict__ te,
    const float* __restrict__ gg, const float* __restrict__ gb,
    const float* __restrict__ ug, const float* __restrict__ ub,
    const float* __restrict__ gbp, const float* __restrict__ ubp,
    float* __restrict__ eg, float* __restrict__ eu,
    f16* __restrict__ egh, f16* __restrict__ euh,
    float* __restrict__ biasg, float* __restrict__ biasu) {
  __shared__ float esg[4][64];
  __shared__ float esu[4][64];
  int nl = threadIdx.x >> 6;
  int node = blockIdx.x * 4 + nl;
  int d = threadIdx.x & 63;
  float v = ne[node * DD + d] + te[d];
  float s = v;
  #pragma unroll
  for (int m = 1; m < 64; m <<= 1) s += __shfl_xor(s, m, 64);
  float mu = s * (1.f / 64.f);
  float df = v - mu;
  float q = df * df;
  #pragma unroll
  for (int m = 1; m < 64; m <<= 1) q += __shfl_xor(q, m, 64);
  float rs = rsqrtf(q * (1.f / 64.f) + 1e-12f);
  float base = df * rs;
  float a = base * gg[d] + gb[d];
  float b = base * ug[d] + ub[d];
  eg[node * DD + d] = a; egh[node * DD + d] = (f16)a;
  eu[node * DD + d] = b; euh[node * DD + d] = (f16)b;
  esg[nl][d] = a; esu[nl][d] = b;
  __syncthreads();
  // 4 nodes x 192 outputs = 768 units; thread t does units t, t+256, t+512
  #pragma unroll
  for (int i = 0; i < 3; ++i) {
    int u = i * 256 + threadIdx.x;
    int un = u / 192, oo = u % 192;
    int n2 = blockIdx.x * 4 + un;
    float acc = 0.f;
    if (oo < OG) {
      #pragma unroll 8
      for (int dd = 0; dd < 64; ++dd) acc += esg[un][dd] * gbp[dd * OG + oo];
      biasg[(size_t)n2 * OG + oo] = acc;
    } else {
      int o = oo - OG;
      #pragma unroll 8
      for (int dd = 0; dd < 64; ++dd) acc += esu[un][dd] * ubp[dd * OU + o];
      biasu[(size_t)n2 * OU + o] = acc;
    }
  }
}

// ---------------- wpool (d,ki,o) f32 -> wpool_t (o*KI+ki, d) fp16 ; z selects gate/update ----------
__global__ __launch_bounds__(256) void k_wpool_t(const float* __restrict__ gwp,
                                                 const float* __restrict__ uwp,
                                                 f16* __restrict__ wtg,
                                                 f16* __restrict__ wtu) {
  const int upd = blockIdx.z;
  if (upd && blockIdx.y >= OU / 16) return;
  const float* wpool = upd ? uwp : gwp;
  f16* wt = upd ? wtu : wtg;
  const int O = upd ? OU : OG;
  __shared__ float tile[64][17];
  int ki = blockIdx.x;
  int o0 = blockIdx.y * 16;
  int t = threadIdx.x;
  #pragma unroll
  for (int i = 0; i < 4; ++i) {
    int e2 = i * 256 + t;
    int d = e2 >> 4, o = e2 & 15;
    tile[d][o] = wpool[((size_t)d * KI + ki) * O + o0 + o];
  }
  __syncthreads();
  #pragma unroll
  for (int i = 0; i < 4; ++i) {
    int e2 = i * 256 + t;
    int o = e2 >> 6, d = e2 & 63;
    wt[((size_t)(o0 + o) * KI + ki) * DD + d] = (f16)tile[d][o];
  }
}

// ------- build cm[b][c][m], xg[m][b][c] (c<96), sth[b][m][o] f16 in one pass -------
__global__ __launch_bounds__(256) void k_build_inp(const float* __restrict__ x,
                                                   const float* __restrict__ st,
                                                   f16* __restrict__ cm,
                                                   f16* __restrict__ xg,
                                                   f16* __restrict__ sth) {
  __shared__ f16 tile[96][66];
  int mb = blockIdx.x * 64;
  int b = blockIdx.y;
  int t = threadIdx.x;
  #pragma unroll
  for (int i = 0; i < 24; ++i) {
    int e2 = i * 256 + t;  // 0..6143
    int m = e2 / 96, c = e2 % 96;
    float v = (c < CINC) ? x[((size_t)b * NN + mb + m) * CINC + c]
                         : st[((size_t)b * NN + mb + m) * HH + c - CINC];
    f16 h = (f16)v;
    tile[c][m] = h;
    xg[((size_t)(mb + m) * BB + b) * KI + c] = h;
    if (c >= CINC) sth[((size_t)b * NN + mb + m) * HH + c - CINC] = h;
  }
  __syncthreads();
  #pragma unroll
  for (int i = 0; i < 24; ++i) {
    int e2 = i * 256 + t;
    int c = e2 >> 6, m = e2 & 63;
    cm[((size_t)b * C1 + c) * NN + mb + m] = tile[c][m];
  }
}

// ---------------- zs[b][m][o] -> cand_cm[b][32+o][m] ----------------
__global__ __launch_bounds__(256) void k_transpose_zs(const f16* __restrict__ zs,
                                                      f16* __restrict__ cm) {
  __shared__ f16 tile[64][66];
  int mb = blockIdx.x * 64;
  int b = blockIdx.y;
  int t = threadIdx.x;
  #pragma unroll
  for (int i = 0; i < 16; ++i) {
    int e2 = i * 256 + t;
    int m = e2 >> 6, o = e2 & 63;
    tile[o][m] = zs[((size_t)b * NN + mb + m) * HH + o];
  }
  __syncthreads();
  #pragma unroll
  for (int i = 0; i < 16; ++i) {
    int e2 = i * 256 + t;
    int o = e2 >> 6, m = e2 & 63;
    cm[((size_t)b * C1 + CINC + o) * NN + mb + m] = tile[o][m];
  }
}

// ---------------- S = e @ e^T  (f32, 32x32 tiles) ----------------
__global__ __launch_bounds__(256) void k_scores(const float* __restrict__ e,
                                                float* __restrict__ S) {
  __shared__ float er[32][65];
  __shared__ float ec[32][65];
  int rb = blockIdx.y * 32, cbb = blockIdx.x * 32;
  int t = threadIdx.x;
  {
    int row = t >> 3;
    int d0 = (t & 7) * 8;
    const float* pr = &e[(size_t)(rb + row) * DD + d0];
    const float* pc = &e[(size_t)(cbb + row) * DD + d0];
    #pragma unroll
    for (int j = 0; j < 8; ++j) { er[row][d0 + j] = pr[j]; ec[row][d0 + j] = pc[j]; }
  }
  __syncthreads();
  int r = t >> 5;   // 0..7
  int c = t & 31;
  float a0 = 0.f, a1 = 0.f, a2 = 0.f, a3 = 0.f;
  #pragma unroll 8
  for (int d = 0; d < 64; ++d) {
    float vc = ec[c][d];
    a0 += er[r][d] * vc;
    a1 += er[r + 8][d] * vc;
    a2 += er[r + 16][d] * vc;
    a3 += er[r + 24][d] * vc;
  }
  S[(size_t)(rb + r) * NN + cbb + c] = a0;
  S[(size_t)(rb + r + 8) * NN + cbb + c] = a1;
  S[(size_t)(rb + r + 16) * NN + cbb + c] = a2;
  S[(size_t)(rb + r + 24) * NN + cbb + c] = a3;
}

// ---------------- row softmax -> adj fp16 ----------------
__global__ __launch_bounds__(256) void k_softmax(const float* __restrict__ S,
                                                 f16* __restrict__ adj) {
  int n = blockIdx.x;
  int t = threadIdx.x;
  const float* row = S + (size_t)n * NN;
  float v[8];
  float mx = -3.0e38f;
  #pragma unroll
  for (int i = 0; i < 8; ++i) { v[i] = row[t + i * 256]; mx = fmaxf(mx, v[i]); }
  #pragma unroll
  for (int m = 1; m < 64; m <<= 1) mx = fmaxf(mx, __shfl_xor(mx, m, 64));
  __shared__ float redm[4];
  if ((t & 63) == 0) redm[t >> 6] = mx;
  __syncthreads();
  mx = fmaxf(fmaxf(redm[0], redm[1]), fmaxf(redm[2], redm[3]));
  float s = 0.f;
  #pragma unroll
  for (int i = 0; i < 8; ++i) { v[i] = expf(v[i] - mx); s += v[i]; }
  #pragma unroll
  for (int m = 1; m < 64; m <<= 1) s += __shfl_xor(s, m, 64);
  __shared__ float reds[4];
  if ((t & 63) == 0) reds[t >> 6] = s;
  __syncthreads();
  s = reds[0] + reds[1] + reds[2] + reds[3];
  float inv = 1.f / s;
  #pragma unroll
  for (int i = 0; i < 8; ++i) adj[(size_t)n * NN + t + i * 256] = (f16)(v[i] * inv);
}

// ---------------- xa: xg[n][b][96+l] = adj(n,m) @ cm(b*96+l, m)^T ----------------
// 64x96 tile, BK=64, dbuf + counted-vmcnt pipeline, XCD-chunked block decode:
// each XCD owns 4 cm panels (1.5 MB, L2-resident) and sweeps all nb.
#define BM 64
#define BN 96

__global__ __launch_bounds__(256, 4) void k_gemm_xa(const f16* __restrict__ A,
                                                    const f16* __restrict__ Bm,
                                                    f16* __restrict__ xg) {
  const int orig = blockIdx.x;          // 0..1023
  const int xcd = orig & 7, j = orig >> 3;
  const int nb = (j >> 2) * BM;
  const int by = (xcd << 2) + (j & 3);  // 4 consecutive by per XCD
  const int cb = by * BN;
  const int tid = threadIdx.x;
  const int w = tid >> 6, lane = tid & 63;
  const int wr = (w >> 1) * 32, wc = (w & 1) * 48;
  const int fr = lane & 15, fq = lane >> 4;

  const int arow = tid >> 3;                               // 0..31
  const int acolb = ((tid & 7) * 16) ^ ((arow & 7) << 4);  // pre-swizzled, j-invariant
  const char* asrc = (const char*)A + (size_t)(nb + arow) * (NN * 2) + acolb;
  const char* bsrc = (const char*)Bm + (size_t)(cb + arow) * (NN * 2) + acolb;

  __shared__ f16 Al[2][BM * 64];
  __shared__ f16 Bl[2][BN * 64];
  auto stage = [&](int buf, int kt) {   // 5 x global_load_lds per wave
    const size_t ko = (size_t)kt * 2;
    char* ad = (char*)&Al[buf][0] + (w << 10);
    char* bd = (char*)&Bl[buf][0] + (w << 10);
    gl_lds16(asrc + ko, ad);
    gl_lds16(asrc + ko + (size_t)32 * (NN * 2), ad + 4096);
    gl_lds16(bsrc + ko, bd);
    gl_lds16(bsrc + ko + (size_t)32 * (NN * 2), bd + 4096);
    gl_lds16(bsrc + ko + (size_t)64 * (NN * 2), bd + 8192);
  };

  f32x4 acc[2][3] = {};
  stage(0, 0);
  for (int kt = 0; kt < NN; kt += 64) {
    const int cur = (kt >> 6) & 1;
    if (kt + 64 < NN) {
      stage(cur ^ 1, kt + 64);
      asm volatile("s_waitcnt vmcnt(5)" ::: "memory");   // my stage(cur) landed
    } else {
      asm volatile("s_waitcnt vmcnt(0)" ::: "memory");
    }
    __builtin_amdgcn_sched_barrier(0);
    __builtin_amdgcn_s_barrier();                         // A: buf[cur] ready (all waves)
    const char* Ab = (const char*)&Al[cur][0];
    const char* Bb = (const char*)&Bl[cur][0];
    half8 af[2][2], bf[2][3];
    #pragma unroll
    for (int k0 = 0; k0 < 2; ++k0) {
      const int kb = k0 * 64 + fq * 16;
      #pragma unroll
      for (int mt = 0; mt < 2; ++mt)
        af[k0][mt] = *(const half8*)(Ab + SWZ(wr + mt * 16 + fr, kb));
      #pragma unroll
      for (int nt = 0; nt < 3; ++nt)
        bf[k0][nt] = *(const half8*)(Bb + SWZ(wc + nt * 16 + fr, kb));
    }
    asm volatile("s_waitcnt lgkmcnt(0)" ::: "memory");    // my reads of buf[cur] done
    __builtin_amdgcn_sched_barrier(0);
    __builtin_amdgcn_s_barrier();                         // B: release buf[cur] for restage
    #pragma unroll
    for (int k0 = 0; k0 < 2; ++k0)
      #pragma unroll
      for (int mt = 0; mt < 2; ++mt)
        #pragma unroll
        for (int nt = 0; nt < 3; ++nt)
          acc[mt][nt] = mfma16(af[k0][mt], bf[k0][nt], acc[mt][nt]);
  }
  #pragma unroll
  for (int mt = 0; mt < 2; ++mt)
    #pragma unroll
    for (int nt = 0; nt < 3; ++nt)
      #pragma unroll
      for (int r = 0; r < 4; ++r) {
        int n = nb + wr + mt * 16 + fq * 4 + r;
        int l = wc + nt * 16 + fr;         // 0..95
        xg[((size_t)n * BB + by) * KI + 96 + l] = (f16)acc[mt][nt][r];
      }
}

// ---------------- W(all nodes): W[n][c] = e(n,:) . wt(c, :), c = o*KI+ki ----------------
// GEMM M=2048, N=ncols, K=64. 128x128 tiles, LDS-staged, swizzled.
__global__ __launch_bounds__(256) void k_gemm_w2(const f16* __restrict__ A,
                                                 const f16* __restrict__ B,
                                                 f16* __restrict__ W, int ncols) {
  __shared__ f16 Al[128 * 64];
  __shared__ f16 Bl[128 * 64];
  const int cb = blockIdx.x * 128;
  const int nb = blockIdx.y * 128;
  const int tid = threadIdx.x;
  const int w = tid >> 6, lane = tid & 63;
  const int wr = (w >> 1) * 64, wc = (w & 1) * 64;
  const int fr = lane & 15, fq = lane >> 4;
  const int arow = tid >> 3;
  const int acolb = ((tid & 7) * 16) ^ ((arow & 7) << 4);
  const char* asrc = (const char*)A + (size_t)(nb + arow) * 128 + acolb;
  const char* bsrc = (const char*)B + (size_t)(cb + arow) * 128 + acolb;
  char* ad = (char*)Al + (w << 10);
  char* bd = (char*)Bl + (w << 10);
  #pragma unroll
  for (int j = 0; j < 4; ++j) gl_lds16(asrc + (size_t)j * 32 * 128, ad + j * 4096);
  #pragma unroll
  for (int j = 0; j < 4; ++j) gl_lds16(bsrc + (size_t)j * 32 * 128, bd + j * 4096);
  __syncthreads();
  f32x4 acc[4][4] = {};
  #pragma unroll
  for (int k0 = 0; k0 < 2; ++k0) {
    const int kb = k0 * 64 + fq * 16;
    half8 af[4], bf[4];
    #pragma unroll
    for (int mt = 0; mt < 4; ++mt)
      af[mt] = *(const half8*)((const char*)Al + SWZ(wr + mt * 16 + fr, kb));
    #pragma unroll
    for (int nt = 0; nt < 4; ++nt)
      bf[nt] = *(const half8*)((const char*)Bl + SWZ(wc + nt * 16 + fr, kb));
    #pragma unroll
    for (int mt = 0; mt < 4; ++mt)
      #pragma unroll
      for (int nt = 0; nt < 4; ++nt)
        acc[mt][nt] = mfma16(af[mt], bf[nt], acc[mt][nt]);
  }
  #pragma unroll
  for (int mt = 0; mt < 4; ++mt)
    #pragma unroll
    for (int nt = 0; nt < 4; ++nt)
      #pragma unroll
      for (int r = 0; r < 4; ++r) {
        int n = nb + wr + mt * 16 + fq * 4 + r;
        int c = cb + wc + nt * 16 + fr;
        W[(size_t)n * ncols + c] = (f16)acc[mt][nt][r];
      }
}

// ---------------- apply: out(b,n,o) = xg(n,b,:) . W[n](o,:) + bias, + epilogues ----------------
// GATE: o in [0,128): o<64 = z (writes xg z-slice + zs), o>=64 = r (writes rbuf).
// !GATE (update): o in [0,64): writes final out.
template <bool GATE>
__global__ __launch_bounds__(256) void k_apply3(
    const f16* __restrict__ xg, const f16* __restrict__ W,
    const float* __restrict__ bias,
    const f16* __restrict__ sth,
    f16* xgw, f16* __restrict__ zs, f16* __restrict__ rbuf,
    float* __restrict__ outp) {
  constexpr int WS = GATE ? WCG : WCU;
  constexpr int NOT_ = GATE ? 2 : 1;
  constexpr int BSTR = GATE ? OG : OU;
  const int n = blockIdx.x;
  const int lane = threadIdx.x & 63, w = threadIdx.x >> 6;
  const int fr = lane & 15, fq = lane >> 4;
  half8 af[2][6];
  #pragma unroll
  for (int mt = 0; mt < 2; ++mt) {
    const f16* arow = xg + ((size_t)n * BB + mt * 16 + fr) * KI;
    #pragma unroll
    for (int ks = 0; ks < 6; ++ks)
      af[mt][ks] = *(const half8*)&arow[ks * 32 + fq * 8];
  }
  if (GATE) __syncthreads();  // all A reads before z-slice writes to xg
  f32x4 acc[2][NOT_] = {};
  #pragma unroll
  for (int ks = 0; ks < 6; ++ks) {
    #pragma unroll
    for (int ot = 0; ot < NOT_; ++ot) {
      int o = (GATE ? (w * 2 + ot) : w) * 16 + fr;
      half8 bf = *(const half8*)&W[(size_t)n * WS + (size_t)o * KI + ks * 32 + fq * 8];
      #pragma unroll
      for (int mt = 0; mt < 2; ++mt) acc[mt][ot] = mfma16(af[mt][ks], bf, acc[mt][ot]);
    }
  }
  #pragma unroll
  for (int mt = 0; mt < 2; ++mt)
    #pragma unroll
    for (int ot = 0; ot < NOT_; ++ot) {
      const int o = (GATE ? (w * 2 + ot) : w) * 16 + fr;
      const float bs = bias[(size_t)n * BSTR + o];
      #pragma unroll
      for (int r = 0; r < 4; ++r) {
        int b = mt * 16 + fq * 4 + r;
        float val = acc[mt][ot][r] + bs;
        if (GATE) {
          float s = 1.f / (1.f + expf(-val));
          if (o < HH) {
            size_t bno = ((size_t)b * NN + n) * HH + o;
            float zst = s * (float)sth[bno];
            xgw[((size_t)n * BB + b) * KI + CINC + o] = (f16)zst;
            zs[bno] = (f16)zst;
          } else {
            rbuf[((size_t)b * NN + n) * HH + (o - HH)] = (f16)s;
          }
        } else {
          size_t bno = ((size_t)b * NN + n) * HH + o;
          float hc = tanhf(val);
          float rr = (float)rbuf[bno];
          outp[bno] = rr * (float)sth[bno] + (1.f - rr) * hc;
        }
      }
    }
}

extern "C" void kernel_launch(void* const* d_in, const int* in_sizes, int n_in,
                              void* d_out, int out_size, void* d_ws, size_t ws_size,
                              hipStream_t stream) {
  const float* x   = (const float*)d_in[0];
  const float* st  = (const float*)d_in[1];
  const float* ne  = (const float*)d_in[2];
  const float* te  = (const float*)d_in[3];
  const float* gwp = (const float*)d_in[4];
  const float* gbp = (const float*)d_in[5];
  const float* gg  = (const float*)d_in[6];
  const float* gb  = (const float*)d_in[7];
  const float* uwp = (const float*)d_in[8];
  const float* ubp = (const float*)d_in[9];
  const float* ug  = (const float*)d_in[10];
  const float* ub  = (const float*)d_in[11];
  float* out = (float*)d_out;

  char* wsb = (char*)d_ws;
  size_t off = 0;
  auto alloc = [&](size_t bytes) {
    char* p = wsb + off;
    off = (off + bytes + 255) & ~(size_t)255;
    return p;
  };
  float* e_g   = (float*)alloc((size_t)NN * DD * 4);
  float* e_u   = (float*)alloc((size_t)NN * DD * 4);
  f16*   egh   = (f16*)  alloc((size_t)NN * DD * 2);
  f16*   euh   = (f16*)  alloc((size_t)NN * DD * 2);
  float* biasg = (float*)alloc((size_t)NN * OG * 4);
  float* biasu = (float*)alloc((size_t)NN * OU * 4);
  f16*   wtg   = (f16*)  alloc((size_t)WCG * DD * 2);       //  3 MB
  f16*   wtu   = (f16*)  alloc((size_t)WCU * DD * 2);       // 1.5 MB
  f16*   xg    = (f16*)  alloc((size_t)NN * BB * KI * 2);   // 24 MB
  f16*   cm    = (f16*)  alloc((size_t)BB * C1 * NN * 2);   // 12 MB
  f16*   zs    = (f16*)  alloc((size_t)BB * NN * HH * 2);   //  8 MB
  f16*   rbuf  = (f16*)  alloc((size_t)BB * NN * HH * 2);   //  8 MB
  f16*   sth   = (f16*)  alloc((size_t)BB * NN * HH * 2);   //  8 MB
  f16*   adj   = (f16*)  alloc((size_t)NN * NN * 2);        //  8 MB
  char*  Wreg  =         alloc((size_t)NN * WCG * 2);       // 96 MB; S aliases head
  float* S     = (float*)Wreg;                               // 16 MB (dead before W written)
  f16*   W     = (f16*)Wreg;
  (void)ws_size; (void)in_sizes; (void)n_in; (void)out_size;

  hipLaunchKernelGGL(k_ln_bias, dim3(NN / 4), dim3(256), 0, stream,
                     ne, te, gg, gb, ug, ub, gbp, ubp,
                     e_g, e_u, egh, euh, biasg, biasu);
  hipLaunchKernelGGL(k_wpool_t, dim3(KI, OG / 16, 2), dim3(256), 0, stream,
                     gwp, uwp, wtg, wtu);
  hipLaunchKernelGGL(k_build_inp, dim3(NN / 64, BB), dim3(256), 0, stream,
                     x, st, cm, xg, sth);

  // ---- gate GCN ----
  hipLaunchKernelGGL(k_scores, dim3(NN / 32, NN / 32), dim3(256), 0, stream, e_g, S);
  hipLaunchKernelGGL(k_softmax, dim3(NN), dim3(256), 0, stream, S, adj);
  hipLaunchKernelGGL(k_gemm_xa, dim3(1024), dim3(256), 0, stream, adj, cm, xg);
  hipLaunchKernelGGL(k_gemm_w2, dim3(WCG / 128, NN / 128), dim3(256), 0, stream,
                     egh, wtg, W, WCG);
  hipLaunchKernelGGL((k_apply3<true>), dim3(NN), dim3(256), 0, stream,
                     xg, W, biasg, sth, xg, zs, rbuf, (float*)nullptr);
  hipLaunchKernelGGL(k_transpose_zs, dim3(NN / 64, BB), dim3(256), 0, stream, zs, cm);

  // ---- update GCN ----
  hipLaunchKernelGGL(k_scores, dim3(NN / 32, NN / 32), dim3(256), 0, stream, e_u, S);
  hipLaunchKernelGGL(k_softmax, dim3(NN), dim3(256), 0, stream, S, adj);
  hipLaunchKernelGGL(k_gemm_xa, dim3(1024), dim3(256), 0, stream, adj, cm, xg);
  hipLaunchKernelGGL(k_gemm_w2, dim3(WCU / 128, NN / 128), dim3(256), 0, stream,
                     euh, wtu, W, WCU);
  hipLaunchKernelGGL((k_apply3<false>), dim3(NN), dim3(256), 0, stream,
                     xg, W, biasu, sth, (f16*)nullptr, (f16*)nullptr, rbuf, out);
}

// Round 6
// 234.727 us; speedup vs baseline: 1.9131x; 1.0455x over previous
//
#include <hip/hip_runtime.h>

typedef _Float16 f16;
typedef _Float16 half8 __attribute__((ext_vector_type(8)));
typedef float f32x4 __attribute__((ext_vector_type(4)));

#define NN 2048
#define BB 32
#define CINC 32
#define HH 64
#define DD 64
#define C1 96      // CIN + H
#define KI 192     // 2 * C1
#define OG 128
#define OU 64
#define WCG 24576  // OG * KI
#define WCU 12288  // OU * KI

// xg layout: [n][ks][b][kk]  (ks = ki>>5, kk = ki&31)
#define XGI(n, ks, b, kk) (((((size_t)(n)) * 6 + (ks)) * BB + (b)) * 32 + (kk))

__device__ __forceinline__ f32x4 mfma16(half8 a, half8 b, f32x4 c) {
  return __builtin_amdgcn_mfma_f32_16x16x32_f16(a, b, c, 0, 0, 0);
}

typedef __attribute__((address_space(1))) const void* gas_t;
typedef __attribute__((address_space(3))) void* las_t;
__device__ __forceinline__ void gl_lds16(const void* g, void* l) {
  __builtin_amdgcn_global_load_lds((gas_t)g, (las_t)l, 16, 0, 0);
}

// XOR swizzle for 128B-row LDS tiles (rule #21: pre-swizzled source + swizzled read)
#define SWZ(row, kb) (((row) << 7) + ((kb) ^ (((row) & 7) << 4)))

// ------- LayerNorm -> e (gate & update) + both bias projections, one launch -------
__global__ __launch_bounds__(256) void k_ln_bias(
    const float* __restrict__ ne, const float* __restrict__ te,
    const float* __restrict__ gg, const float* __restrict__ gb,
    const float* __restrict__ ug, const float* __restrict__ ub,
    const float* __restrict__ gbp, const float* __restrict__ ubp,
    float* __restrict__ eg, float* __restrict__ eu,
    f16* __restrict__ egh, f16* __restrict__ euh,
    float* __restrict__ biasg, float* __restrict__ biasu) {
  __shared__ float esg[4][64];
  __shared__ float esu[4][64];
  int nl = threadIdx.x >> 6;
  int node = blockIdx.x * 4 + nl;
  int d = threadIdx.x & 63;
  float v = ne[node * DD + d] + te[d];
  float s = v;
  #pragma unroll
  for (int m = 1; m < 64; m <<= 1) s += __shfl_xor(s, m, 64);
  float mu = s * (1.f / 64.f);
  float df = v - mu;
  float q = df * df;
  #pragma unroll
  for (int m = 1; m < 64; m <<= 1) q += __shfl_xor(q, m, 64);
  float rs = rsqrtf(q * (1.f / 64.f) + 1e-12f);
  float base = df * rs;
  float a = base * gg[d] + gb[d];
  float b = base * ug[d] + ub[d];
  eg[node * DD + d] = a; egh[node * DD + d] = (f16)a;
  eu[node * DD + d] = b; euh[node * DD + d] = (f16)b;
  esg[nl][d] = a; esu[nl][d] = b;
  __syncthreads();
  #pragma unroll
  for (int i = 0; i < 3; ++i) {
    int u = i * 256 + threadIdx.x;
    int un = u / 192, oo = u % 192;
    int n2 = blockIdx.x * 4 + un;
    float acc = 0.f;
    if (oo < OG) {
      #pragma unroll 8
      for (int dd = 0; dd < 64; ++dd) acc += esg[un][dd] * gbp[dd * OG + oo];
      biasg[(size_t)n2 * OG + oo] = acc;
    } else {
      int o = oo - OG;
      #pragma unroll 8
      for (int dd = 0; dd < 64; ++dd) acc += esu[un][dd] * ubp[dd * OU + o];
      biasu[(size_t)n2 * OU + o] = acc;
    }
  }
}

// ------- wpool (d,ki,o) f32 -> wt rows in (ks,o,kk) order: row = (ks*O+o)*32+kk -------
__global__ __launch_bounds__(256) void k_wpool_t(const float* __restrict__ gwp,
                                                 const float* __restrict__ uwp,
                                                 f16* __restrict__ wtg,
                                                 f16* __restrict__ wtu) {
  const int upd = blockIdx.z;
  if (upd && blockIdx.y >= OU / 16) return;
  const float* wpool = upd ? uwp : gwp;
  f16* wt = upd ? wtu : wtg;
  const int O = upd ? OU : OG;
  __shared__ float tile[64][17];
  int ki = blockIdx.x;
  int o0 = blockIdx.y * 16;
  int t = threadIdx.x;
  const int ks = ki >> 5, kk = ki & 31;
  #pragma unroll
  for (int i = 0; i < 4; ++i) {
    int e2 = i * 256 + t;
    int d = e2 >> 4, o = e2 & 15;
    tile[d][o] = wpool[((size_t)d * KI + ki) * O + o0 + o];
  }
  __syncthreads();
  #pragma unroll
  for (int i = 0; i < 4; ++i) {
    int e2 = i * 256 + t;
    int o = e2 >> 6, d = e2 & 63;
    size_t row = ((size_t)ks * O + (o0 + o)) * 32 + kk;
    wt[row * DD + d] = (f16)tile[d][o];
  }
}

// ------- build cm[b][c][m], xg'[m][ks][b][kk] (c<96), sth[b][m][o] f16 in one pass -------
__global__ __launch_bounds__(256) void k_build_inp(const float* __restrict__ x,
                                                   const float* __restrict__ st,
                                                   f16* __restrict__ cm,
                                                   f16* __restrict__ xg,
                                                   f16* __restrict__ sth) {
  __shared__ f16 tile[96][66];
  int mb = blockIdx.x * 64;
  int b = blockIdx.y;
  int t = threadIdx.x;
  #pragma unroll
  for (int i = 0; i < 24; ++i) {
    int e2 = i * 256 + t;  // 0..6143
    int m = e2 / 96, c = e2 % 96;
    float v = (c < CINC) ? x[((size_t)b * NN + mb + m) * CINC + c]
                         : st[((size_t)b * NN + mb + m) * HH + c - CINC];
    f16 h = (f16)v;
    tile[c][m] = h;
    xg[XGI(mb + m, c >> 5, b, c & 31)] = h;
    if (c >= CINC) sth[((size_t)b * NN + mb + m) * HH + c - CINC] = h;
  }
  __syncthreads();
  #pragma unroll
  for (int i = 0; i < 24; ++i) {
    int e2 = i * 256 + t;
    int c = e2 >> 6, m = e2 & 63;
    cm[((size_t)b * C1 + c) * NN + mb + m] = tile[c][m];
  }
}

// ---------------- zs[b][m][o] -> cand_cm[b][32+o][m] ----------------
__global__ __launch_bounds__(256) void k_transpose_zs(const f16* __restrict__ zs,
                                                      f16* __restrict__ cm) {
  __shared__ f16 tile[64][66];
  int mb = blockIdx.x * 64;
  int b = blockIdx.y;
  int t = threadIdx.x;
  #pragma unroll
  for (int i = 0; i < 16; ++i) {
    int e2 = i * 256 + t;
    int m = e2 >> 6, o = e2 & 63;
    tile[o][m] = zs[((size_t)b * NN + mb + m) * HH + o];
  }
  __syncthreads();
  #pragma unroll
  for (int i = 0; i < 16; ++i) {
    int e2 = i * 256 + t;
    int o = e2 >> 6, m = e2 & 63;
    cm[((size_t)b * C1 + CINC + o) * NN + mb + m] = tile[o][m];
  }
}

// ---------------- S = e @ e^T  (f32, 32x32 tiles) ----------------
__global__ __launch_bounds__(256) void k_scores(const float* __restrict__ e,
                                                float* __restrict__ S) {
  __shared__ float er[32][65];
  __shared__ float ec[32][65];
  int rb = blockIdx.y * 32, cbb = blockIdx.x * 32;
  int t = threadIdx.x;
  {
    int row = t >> 3;
    int d0 = (t & 7) * 8;
    const float* pr = &e[(size_t)(rb + row) * DD + d0];
    const float* pc = &e[(size_t)(cbb + row) * DD + d0];
    #pragma unroll
    for (int j = 0; j < 8; ++j) { er[row][d0 + j] = pr[j]; ec[row][d0 + j] = pc[j]; }
  }
  __syncthreads();
  int r = t >> 5;   // 0..7
  int c = t & 31;
  float a0 = 0.f, a1 = 0.f, a2 = 0.f, a3 = 0.f;
  #pragma unroll 8
  for (int d = 0; d < 64; ++d) {
    float vc = ec[c][d];
    a0 += er[r][d] * vc;
    a1 += er[r + 8][d] * vc;
    a2 += er[r + 16][d] * vc;
    a3 += er[r + 24][d] * vc;
  }
  S[(size_t)(rb + r) * NN + cbb + c] = a0;
  S[(size_t)(rb + r + 8) * NN + cbb + c] = a1;
  S[(size_t)(rb + r + 16) * NN + cbb + c] = a2;
  S[(size_t)(rb + r + 24) * NN + cbb + c] = a3;
}

// ---------------- row softmax -> adj fp16 ----------------
__global__ __launch_bounds__(256) void k_softmax(const float* __restrict__ S,
                                                 f16* __restrict__ adj) {
  int n = blockIdx.x;
  int t = threadIdx.x;
  const float* row = S + (size_t)n * NN;
  float v[8];
  float mx = -3.0e38f;
  #pragma unroll
  for (int i = 0; i < 8; ++i) { v[i] = row[t + i * 256]; mx = fmaxf(mx, v[i]); }
  #pragma unroll
  for (int m = 1; m < 64; m <<= 1) mx = fmaxf(mx, __shfl_xor(mx, m, 64));
  __shared__ float redm[4];
  if ((t & 63) == 0) redm[t >> 6] = mx;
  __syncthreads();
  mx = fmaxf(fmaxf(redm[0], redm[1]), fmaxf(redm[2], redm[3]));
  float s = 0.f;
  #pragma unroll
  for (int i = 0; i < 8; ++i) { v[i] = expf(v[i] - mx); s += v[i]; }
  #pragma unroll
  for (int m = 1; m < 64; m <<= 1) s += __shfl_xor(s, m, 64);
  __shared__ float reds[4];
  if ((t & 63) == 0) reds[t >> 6] = s;
  __syncthreads();
  s = reds[0] + reds[1] + reds[2] + reds[3];
  float inv = 1.f / s;
  #pragma unroll
  for (int i = 0; i < 8; ++i) adj[(size_t)n * NN + t + i * 256] = (f16)(v[i] * inv);
}

// ---------------- xa: xg'[n][ks][by][kk] (ki=96+l) = adj(n,m) @ cm(b*96+l, m)^T ----------------
#define BM 64
#define BN 96

__global__ __launch_bounds__(256, 4) void k_gemm_xa(const f16* __restrict__ A,
                                                    const f16* __restrict__ Bm,
                                                    f16* __restrict__ xg) {
  const int orig = blockIdx.x;          // 0..1023
  const int xcd = orig & 7, j = orig >> 3;
  const int nb = (j >> 2) * BM;
  const int by = (xcd << 2) + (j & 3);  // 4 consecutive by per XCD
  const int cb = by * BN;
  const int tid = threadIdx.x;
  const int w = tid >> 6, lane = tid & 63;
  const int wr = (w >> 1) * 32, wc = (w & 1) * 48;
  const int fr = lane & 15, fq = lane >> 4;

  const int arow = tid >> 3;                               // 0..31
  const int acolb = ((tid & 7) * 16) ^ ((arow & 7) << 4);  // pre-swizzled, j-invariant
  const char* asrc = (const char*)A + (size_t)(nb + arow) * (NN * 2) + acolb;
  const char* bsrc = (const char*)Bm + (size_t)(cb + arow) * (NN * 2) + acolb;

  __shared__ f16 Al[2][BM * 64];
  __shared__ f16 Bl[2][BN * 64];
  auto stage = [&](int buf, int kt) {   // 5 x global_load_lds per wave
    const size_t ko = (size_t)kt * 2;
    char* ad = (char*)&Al[buf][0] + (w << 10);
    char* bd = (char*)&Bl[buf][0] + (w << 10);
    gl_lds16(asrc + ko, ad);
    gl_lds16(asrc + ko + (size_t)32 * (NN * 2), ad + 4096);
    gl_lds16(bsrc + ko, bd);
    gl_lds16(bsrc + ko + (size_t)32 * (NN * 2), bd + 4096);
    gl_lds16(bsrc + ko + (size_t)64 * (NN * 2), bd + 8192);
  };

  f32x4 acc[2][3] = {};
  stage(0, 0);
  for (int kt = 0; kt < NN; kt += 64) {
    const int cur = (kt >> 6) & 1;
    if (kt + 64 < NN) {
      stage(cur ^ 1, kt + 64);
      asm volatile("s_waitcnt vmcnt(5)" ::: "memory");   // my stage(cur) landed
    } else {
      asm volatile("s_waitcnt vmcnt(0)" ::: "memory");
    }
    __builtin_amdgcn_sched_barrier(0);
    __builtin_amdgcn_s_barrier();                         // A: buf[cur] ready (all waves)
    const char* Ab = (const char*)&Al[cur][0];
    const char* Bb = (const char*)&Bl[cur][0];
    half8 af[2][2], bf[2][3];
    #pragma unroll
    for (int k0 = 0; k0 < 2; ++k0) {
      const int kb = k0 * 64 + fq * 16;
      #pragma unroll
      for (int mt = 0; mt < 2; ++mt)
        af[k0][mt] = *(const half8*)(Ab + SWZ(wr + mt * 16 + fr, kb));
      #pragma unroll
      for (int nt = 0; nt < 3; ++nt)
        bf[k0][nt] = *(const half8*)(Bb + SWZ(wc + nt * 16 + fr, kb));
    }
    asm volatile("s_waitcnt lgkmcnt(0)" ::: "memory");    // my reads of buf[cur] done
    __builtin_amdgcn_sched_barrier(0);
    __builtin_amdgcn_s_barrier();                         // B: release buf[cur] for restage
    #pragma unroll
    for (int k0 = 0; k0 < 2; ++k0)
      #pragma unroll
      for (int mt = 0; mt < 2; ++mt)
        #pragma unroll
        for (int nt = 0; nt < 3; ++nt)
          acc[mt][nt] = mfma16(af[k0][mt], bf[k0][nt], acc[mt][nt]);
  }
  #pragma unroll
  for (int mt = 0; mt < 2; ++mt)
    #pragma unroll
    for (int nt = 0; nt < 3; ++nt)
      #pragma unroll
      for (int r = 0; r < 4; ++r) {
        int n = nb + wr + mt * 16 + fq * 4 + r;
        int l = wc + nt * 16 + fr;         // 0..95 -> ki = 96+l
        xg[XGI(n, 3 + (l >> 5), by, l & 31)] = (f16)acc[mt][nt][r];
      }
}

// ---------------- W(all nodes): W[n][c] = e(n,:) . wt(c, :), c = (ks*O+o)*32+kk ----------------
// GEMM M=2048, N=ncols, K=64. 128x128 tiles, LDS-staged, swizzled.
__global__ __launch_bounds__(256) void k_gemm_w2(const f16* __restrict__ A,
                                                 const f16* __restrict__ B,
                                                 f16* __restrict__ W, int ncols) {
  __shared__ f16 Al[128 * 64];
  __shared__ f16 Bl[128 * 64];
  const int cb = blockIdx.x * 128;
  const int nb = blockIdx.y * 128;
  const int tid = threadIdx.x;
  const int w = tid >> 6, lane = tid & 63;
  const int wr = (w >> 1) * 64, wc = (w & 1) * 64;
  const int fr = lane & 15, fq = lane >> 4;
  const int arow = tid >> 3;
  const int acolb = ((tid & 7) * 16) ^ ((arow & 7) << 4);
  const char* asrc = (const char*)A + (size_t)(nb + arow) * 128 + acolb;
  const char* bsrc = (const char*)B + (size_t)(cb + arow) * 128 + acolb;
  char* ad = (char*)Al + (w << 10);
  char* bd = (char*)Bl + (w << 10);
  #pragma unroll
  for (int j = 0; j < 4; ++j) gl_lds16(asrc + (size_t)j * 32 * 128, ad + j * 4096);
  #pragma unroll
  for (int j = 0; j < 4; ++j) gl_lds16(bsrc + (size_t)j * 32 * 128, bd + j * 4096);
  __syncthreads();
  f32x4 acc[4][4] = {};
  #pragma unroll
  for (int k0 = 0; k0 < 2; ++k0) {
    const int kb = k0 * 64 + fq * 16;
    half8 af[4], bf[4];
    #pragma unroll
    for (int mt = 0; mt < 4; ++mt)
      af[mt] = *(const half8*)((const char*)Al + SWZ(wr + mt * 16 + fr, kb));
    #pragma unroll
    for (int nt = 0; nt < 4; ++nt)
      bf[nt] = *(const half8*)((const char*)Bl + SWZ(wc + nt * 16 + fr, kb));
    #pragma unroll
    for (int mt = 0; mt < 4; ++mt)
      #pragma unroll
      for (int nt = 0; nt < 4; ++nt)
        acc[mt][nt] = mfma16(af[mt], bf[nt], acc[mt][nt]);
  }
  #pragma unroll
  for (int mt = 0; mt < 4; ++mt)
    #pragma unroll
    for (int nt = 0; nt < 4; ++nt)
      #pragma unroll
      for (int r = 0; r < 4; ++r) {
        int n = nb + wr + mt * 16 + fq * 4 + r;
        int c = cb + wc + nt * 16 + fr;
        W[(size_t)n * ncols + c] = (f16)acc[mt][nt][r];
      }
}

// ---------------- apply: out(b,n,o) = xg(n,b,:) . W[n](o,:) + bias, + epilogues ----------------
// W layout: [n][(ks*O+o)*32+kk]; xg layout: [n][ks][b][kk] -> 1KB-contiguous wave loads.
template <bool GATE>
__global__ __launch_bounds__(256) void k_apply3(
    const f16* __restrict__ xg, const f16* __restrict__ W,
    const float* __restrict__ bias,
    const f16* __restrict__ sth,
    f16* xgw, f16* __restrict__ zs, f16* __restrict__ rbuf,
    float* __restrict__ outp) {
  constexpr int O = GATE ? OG : OU;
  constexpr int WS = GATE ? WCG : WCU;
  constexpr int NOT_ = GATE ? 2 : 1;
  const int n = blockIdx.x;
  const int lane = threadIdx.x & 63, w = threadIdx.x >> 6;
  const int fr = lane & 15, fq = lane >> 4;
  half8 af[2][6];
  #pragma unroll
  for (int mt = 0; mt < 2; ++mt) {
    #pragma unroll
    for (int ks = 0; ks < 6; ++ks)
      af[mt][ks] = *(const half8*)&xg[XGI(n, ks, mt * 16 + fr, fq * 8)];
  }
  if (GATE) __syncthreads();  // all A reads before z-slice writes to xg
  f32x4 acc[2][NOT_] = {};
  #pragma unroll
  for (int ks = 0; ks < 6; ++ks) {
    #pragma unroll
    for (int ot = 0; ot < NOT_; ++ot) {
      int o = (GATE ? (w * 2 + ot) : w) * 16 + fr;
      half8 bf = *(const half8*)&W[(size_t)n * WS + (((size_t)ks * O + o) << 5) + fq * 8];
      #pragma unroll
      for (int mt = 0; mt < 2; ++mt) acc[mt][ot] = mfma16(af[mt][ks], bf, acc[mt][ot]);
    }
  }
  #pragma unroll
  for (int mt = 0; mt < 2; ++mt)
    #pragma unroll
    for (int ot = 0; ot < NOT_; ++ot) {
      const int o = (GATE ? (w * 2 + ot) : w) * 16 + fr;
      const float bs = bias[(size_t)n * O + o];
      #pragma unroll
      for (int r = 0; r < 4; ++r) {
        int b = mt * 16 + fq * 4 + r;
        float val = acc[mt][ot][r] + bs;
        if (GATE) {
          float s = 1.f / (1.f + expf(-val));
          if (o < HH) {
            size_t bno = ((size_t)b * NN + n) * HH + o;
            float zst = s * (float)sth[bno];
            xgw[XGI(n, 1 + (o >> 5), b, o & 31)] = (f16)zst;  // ki = 32+o
            zs[bno] = (f16)zst;
          } else {
            rbuf[((size_t)b * NN + n) * HH + (o - HH)] = (f16)s;
          }
        } else {
          size_t bno = ((size_t)b * NN + n) * HH + o;
          float hc = tanhf(val);
          float rr = (float)rbuf[bno];
          outp[bno] = rr * (float)sth[bno] + (1.f - rr) * hc;
        }
      }
    }
}

extern "C" void kernel_launch(void* const* d_in, const int* in_sizes, int n_in,
                              void* d_out, int out_size, void* d_ws, size_t ws_size,
                              hipStream_t stream) {
  const float* x   = (const float*)d_in[0];
  const float* st  = (const float*)d_in[1];
  const float* ne  = (const float*)d_in[2];
  const float* te  = (const float*)d_in[3];
  const float* gwp = (const float*)d_in[4];
  const float* gbp = (const float*)d_in[5];
  const float* gg  = (const float*)d_in[6];
  const float* gb  = (const float*)d_in[7];
  const float* uwp = (const float*)d_in[8];
  const float* ubp = (const float*)d_in[9];
  const float* ug  = (const float*)d_in[10];
  const float* ub  = (const float*)d_in[11];
  float* out = (float*)d_out;

  char* wsb = (char*)d_ws;
  size_t off = 0;
  auto alloc = [&](size_t bytes) {
    char* p = wsb + off;
    off = (off + bytes + 255) & ~(size_t)255;
    return p;
  };
  float* e_g   = (float*)alloc((size_t)NN * DD * 4);
  float* e_u   = (float*)alloc((size_t)NN * DD * 4);
  f16*   egh   = (f16*)  alloc((size_t)NN * DD * 2);
  f16*   euh   = (f16*)  alloc((size_t)NN * DD * 2);
  float* biasg = (float*)alloc((size_t)NN * OG * 4);
  float* biasu = (float*)alloc((size_t)NN * OU * 4);
  f16*   wtg   = (f16*)  alloc((size_t)WCG * DD * 2);       //  3 MB
  f16*   wtu   = (f16*)  alloc((size_t)WCU * DD * 2);       // 1.5 MB
  f16*   xg    = (f16*)  alloc((size_t)NN * BB * KI * 2);   // 24 MB
  f16*   cm    = (f16*)  alloc((size_t)BB * C1 * NN * 2);   // 12 MB
  f16*   zs    = (f16*)  alloc((size_t)BB * NN * HH * 2);   //  8 MB
  f16*   rbuf  = (f16*)  alloc((size_t)BB * NN * HH * 2);   //  8 MB
  f16*   sth   = (f16*)  alloc((size_t)BB * NN * HH * 2);   //  8 MB
  f16*   adj   = (f16*)  alloc((size_t)NN * NN * 2);        //  8 MB
  char*  Wreg  =         alloc((size_t)NN * WCG * 2);       // 96 MB; S aliases head
  float* S     = (float*)Wreg;                               // 16 MB (dead before W written)
  f16*   W     = (f16*)Wreg;
  (void)ws_size; (void)in_sizes; (void)n_in; (void)out_size;

  hipLaunchKernelGGL(k_ln_bias, dim3(NN / 4), dim3(256), 0, stream,
                     ne, te, gg, gb, ug, ub, gbp, ubp,
                     e_g, e_u, egh, euh, biasg, biasu);
  hipLaunchKernelGGL(k_wpool_t, dim3(KI, OG / 16, 2), dim3(256), 0, stream,
                     gwp, uwp, wtg, wtu);
  hipLaunchKernelGGL(k_build_inp, dim3(NN / 64, BB), dim3(256), 0, stream,
                     x, st, cm, xg, sth);

  // ---- gate GCN ----
  hipLaunchKernelGGL(k_scores, dim3(NN / 32, NN / 32), dim3(256), 0, stream, e_g, S);
  hipLaunchKernelGGL(k_softmax, dim3(NN), dim3(256), 0, stream, S, adj);
  hipLaunchKernelGGL(k_gemm_xa, dim3(1024), dim3(256), 0, stream, adj, cm, xg);
  hipLaunchKernelGGL(k_gemm_w2, dim3(WCG / 128, NN / 128), dim3(256), 0, stream,
                     egh, wtg, W, WCG);
  hipLaunchKernelGGL((k_apply3<true>), dim3(NN), dim3(256), 0, stream,
                     xg, W, biasg, sth, xg, zs, rbuf, (float*)nullptr);
  hipLaunchKernelGGL(k_transpose_zs, dim3(NN / 64, BB), dim3(256), 0, stream, zs, cm);

  // ---- update GCN ----
  hipLaunchKernelGGL(k_scores, dim3(NN / 32, NN / 32), dim3(256), 0, stream, e_u, S);
  hipLaunchKernelGGL(k_softmax, dim3(NN), dim3(256), 0, stream, S, adj);
  hipLaunchKernelGGL(k_gemm_xa, dim3(1024), dim3(256), 0, stream, adj, cm, xg);
  hipLaunchKernelGGL(k_gemm_w2, dim3(WCU / 128, NN / 128), dim3(256), 0, stream,
                     euh, wtu, W, WCU);
  hipLaunchKernelGGL((k_apply3<false>), dim3(NN), dim3(256), 0, stream,
                     xg, W, biasu, sth, (f16*)nullptr, (f16*)nullptr, rbuf, out);
}